// Round 18
// baseline (377.275 us; speedup 1.0000x reference)
//
#include <hip/hip_runtime.h>
#include <hip/hip_fp8.h>

// GCN: N=100000 nodes, E=1600000 edges, F_IN=F_HID=64, F_OUT=16, fp32.
//
// R29/R30 measured 360.7us (best): split-lane gather_l2 + w3mat confirmed
// the VMEM-issue-rate model (gather_l2 65 -> <=48us, out of top-5).
// New top: matnorm2 48.4us with occupancy 24.6%, VALU 44%, HBM 5%, FETCH
// 12.6MB (B is L2-resident) -- pure wave-starvation: grid 1024 = 4
// blocks/CU = 50% occupancy cap, measured residency ~half that; VGPR 48
// shows w[64] partially reloaded per row, and ~2 waves/SIMD can't hide it.
// R31, single variable: matnorm grids 1024 -> 2048 (8 blocks/CU = the
// 2048-thread cap, 2x residency). Grid-stride loops make this semantics-
// free; cs2 atomics 1024 -> 2048/addr (proven-safe regime). Everything
// else byte-identical to R29/R30.

#define NHB 128     // max hi-buckets of 1024 nodes (N <= 131072); hi = dst >> 10

typedef float floatx2 __attribute__((ext_vector_type(2)));

__device__ __forceinline__ unsigned short f2bf(float f) {
  unsigned u = __builtin_bit_cast(unsigned, f);
  u += 0x7FFFu + ((u >> 16) & 1u);    // round-to-nearest-even
  return (unsigned short)(u >> 16);
}
__device__ __forceinline__ float bf2f(unsigned short h) {
  return __builtin_bit_cast(float, ((unsigned)h) << 16);
}
__device__ __forceinline__ float rlane(float v, int k) {
  return __builtin_bit_cast(
      float, __builtin_amdgcn_readlane(__builtin_bit_cast(int, v), k));
}
__device__ __forceinline__ unsigned char f2fp8(float f) {
  __hip_fp8_e4m3 t(f);                // RNE, saturate-to-finite (OCP)
  return (unsigned char)t.__x;
}
// hardware OCP e4m3 -> f32 (gfx950); exact fallback via f16-embedding.
__device__ __forceinline__ float fp8tof(unsigned v) {
#if __has_builtin(__builtin_amdgcn_cvt_f32_fp8)
  return __builtin_amdgcn_cvt_f32_fp8((int)v, 0);
#else
  const unsigned h = ((v << 8) & 0x8000u) | ((v << 7) & 0x3f80u);
  __half_raw hr; hr.x = (unsigned short)h;
  return (float)__half(hr) * 256.0f;
#endif
}
// packed pair decode: 2 fp8 bytes -> 2 floats in one instruction
__device__ __forceinline__ floatx2 fp8x2tof(unsigned short p) {
#if __has_builtin(__builtin_amdgcn_cvt_pk_f32_fp8)
  return __builtin_amdgcn_cvt_pk_f32_fp8((int)(unsigned)p, false);
#else
  floatx2 r; r.x = fp8tof(p & 0xffu); r.y = fp8tof(p >> 8); return r;
#endif
}

// ------- prelude: cntA histogram of dst (hi-buckets) + column sums of feat -------
__global__ __launch_bounds__(256) void prelude_kernel(
    const int* __restrict__ dst, int* __restrict__ cntA, int E,
    const float* __restrict__ x, float* __restrict__ cs, int n4) {
  __shared__ int lc[NHB];
  __shared__ float lds[16][64];
  const int t = threadIdx.x;
  if (t < NHB) lc[t] = 0;
  __syncthreads();
  const int stride = gridDim.x * blockDim.x;
  for (int e = blockIdx.x * blockDim.x + t; e < E; e += stride)
    atomicAdd(&lc[__builtin_nontemporal_load(&dst[e]) >> 10], 1);

  float s0 = 0.f, s1 = 0.f, s2 = 0.f, s3 = 0.f;
  for (int i = blockIdx.x * blockDim.x + t; i < n4; i += stride) {
    float4 v = ((const float4*)x)[i];
    s0 += v.x; s1 += v.y; s2 += v.z; s3 += v.w;
  }
  const int r = t >> 4;
  const int cq = (t & 15) * 4;
  lds[r][cq + 0] = s0; lds[r][cq + 1] = s1; lds[r][cq + 2] = s2; lds[r][cq + 3] = s3;
  __syncthreads();
  if (t < NHB && lc[t]) atomicAdd(&cntA[t], lc[t]);
  if (t < 64) {
    float tot = 0.f;
    #pragma unroll
    for (int rr = 0; rr < 16; ++rr) tot += lds[rr][t];
    unsafeAtomicAdd(&cs[t], tot);
  }
}

// ------- layer1: z = (x @ W) * rinv - cm, fp8 out; 4-chain FMA -------
__global__ __launch_bounds__(256) void matnorm_kernel(
    const float* x, const float* __restrict__ W,
    const float* __restrict__ cs, unsigned char* __restrict__ z,
    int N, float invN) {
  const int lane = threadIdx.x & 63;
  const int wid  = blockIdx.x * (blockDim.x >> 6) + (threadIdx.x >> 6);
  const int nw   = gridDim.x * (blockDim.x >> 6);

  float w[64];
  float cm0 = 0.f, cm1 = 0.f, cm2 = 0.f, cm3 = 0.f;
  #pragma unroll
  for (int k = 0; k < 64; k += 4) {
    w[k + 0] = W[(k + 0) * 64 + lane];
    w[k + 1] = W[(k + 1) * 64 + lane];
    w[k + 2] = W[(k + 2) * 64 + lane];
    w[k + 3] = W[(k + 3) * 64 + lane];
    cm0 = fmaf(cs[k + 0], w[k + 0], cm0);
    cm1 = fmaf(cs[k + 1], w[k + 1], cm1);
    cm2 = fmaf(cs[k + 2], w[k + 2], cm2);
    cm3 = fmaf(cs[k + 3], w[k + 3], cm3);
  }
  const float cm = ((cm0 + cm1) + (cm2 + cm3)) * invN;

  for (int row = wid; row < N; row += nw) {
    const float xv = x[(size_t)row * 64 + lane];
    float ss = xv * xv;
    #pragma unroll
    for (int m = 1; m < 64; m <<= 1) ss += __shfl_xor(ss, m, 64);
    const float rinv = 1.0f / sqrtf(1e-6f + ss);
    float a0 = 0.f, a1 = 0.f, a2 = 0.f, a3 = 0.f;
    #pragma unroll
    for (int k = 0; k < 64; k += 4) {
      a0 = fmaf(rlane(xv, k + 0), w[k + 0], a0);
      a1 = fmaf(rlane(xv, k + 1), w[k + 1], a1);
      a2 = fmaf(rlane(xv, k + 2), w[k + 2], a2);
      a3 = fmaf(rlane(xv, k + 3), w[k + 3], a3);
    }
    const float acc = (a0 + a1) + (a2 + a3);
    z[(size_t)row * 64 + lane] = f2fp8(acc * rinv - cm);
  }
}

// ------- layer2: z2' = (x @ W) * rinv (UNcentered), fp8 out; cs += colsum(x) -------
__global__ __launch_bounds__(256) void matnorm2_kernel(
    const float* x, const float* __restrict__ W,
    float* __restrict__ cs, unsigned char* __restrict__ z, int N) {
  __shared__ float lred[4][64];
  const int lane = threadIdx.x & 63;
  const int wv   = threadIdx.x >> 6;
  const int wid  = blockIdx.x * (blockDim.x >> 6) + wv;
  const int nw   = gridDim.x * (blockDim.x >> 6);

  float w[64];
  #pragma unroll
  for (int k = 0; k < 64; k += 4) {
    w[k + 0] = W[(k + 0) * 64 + lane];
    w[k + 1] = W[(k + 1) * 64 + lane];
    w[k + 2] = W[(k + 2) * 64 + lane];
    w[k + 3] = W[(k + 3) * 64 + lane];
  }

  float csum = 0.f;
  for (int row = wid; row < N; row += nw) {
    const float xv = x[(size_t)row * 64 + lane];
    csum += xv;
    float ss = xv * xv;
    #pragma unroll
    for (int m = 1; m < 64; m <<= 1) ss += __shfl_xor(ss, m, 64);
    const float rinv = 1.0f / sqrtf(1e-6f + ss);
    float a0 = 0.f, a1 = 0.f, a2 = 0.f, a3 = 0.f;
    #pragma unroll
    for (int k = 0; k < 64; k += 4) {
      a0 = fmaf(rlane(xv, k + 0), w[k + 0], a0);
      a1 = fmaf(rlane(xv, k + 1), w[k + 1], a1);
      a2 = fmaf(rlane(xv, k + 2), w[k + 2], a2);
      a3 = fmaf(rlane(xv, k + 3), w[k + 3], a3);
    }
    const float acc = (a0 + a1) + (a2 + a3);
    z[(size_t)row * 64 + lane] = f2fp8(acc * rinv);
  }
  lred[wv][lane] = csum;
  __syncthreads();
  if (threadIdx.x < 64) {
    const float tot = lred[0][lane] + lred[1][lane] + lred[2][lane] + lred[3][lane];
    unsafeAtomicAdd(&cs[lane], tot);
  }
}

// ------- cm2[m] = invN * sum_k cs2[k] * W2[k][m]  (1 wave) -------
__global__ void cm2_kernel(const float* __restrict__ cs,
                           const float* __restrict__ W,
                           float* __restrict__ cm2, float invN) {
  const int m = threadIdx.x;   // 64
  float a0 = 0.f, a1 = 0.f, a2 = 0.f, a3 = 0.f;
  #pragma unroll
  for (int k = 0; k < 64; k += 4) {
    a0 = fmaf(cs[k + 0], W[(k + 0) * 64 + m], a0);
    a1 = fmaf(cs[k + 1], W[(k + 1) * 64 + m], a1);
    a2 = fmaf(cs[k + 2], W[(k + 2) * 64 + m], a2);
    a3 = fmaf(cs[k + 3], W[(k + 3) * 64 + m], a3);
  }
  cm2[m] = ((a0 + a1) + (a2 + a3)) * invN;
}

// ================= CSR build: hi-bucket radix + LDS counting sort =================
// Edge packed as (src << 10) | (dst & 1023): src < 2^17 -> 27 bits used.

// 128-thread LDS Hillis-Steele exclusive scan over the hi-bucket counts.
__global__ void scanA_kernel(const int* __restrict__ cntA,
                             int* __restrict__ baseA, int* __restrict__ curA,
                             int NHI) {
  __shared__ int s[NHB];
  const int t = threadIdx.x;   // 128
  const int v = (t < NHI) ? cntA[t] : 0;
  s[t] = v;
  __syncthreads();
  int acc = v;
  for (int off = 1; off < NHB; off <<= 1) {
    const int add = (t >= off) ? s[t - off] : 0;
    __syncthreads();
    acc += add;
    s[t] = acc;
    __syncthreads();
  }
  const int excl = acc - v;
  if (t < NHI) { baseA[t] = excl; curA[t] = excl; }
  if (t == NHI - 1) baseA[NHI] = acc;
}

#define TILE 2048
#define CAPA 48   // per-tile per-bucket mean 21, sigma 4.6 -> ~6 sigma + spill
__global__ __launch_bounds__(256) void scatterA_kernel(
    const int* __restrict__ src, const int* __restrict__ dst,
    int* __restrict__ curA, unsigned* __restrict__ ppack, int E) {
  __shared__ unsigned lpk[NHB][CAPA];
  __shared__ int lcnt[NHB], lbase[NHB];
  const int t = threadIdx.x;
  if (t < NHB) lcnt[t] = 0;
  __syncthreads();
  const int ntiles = (E + TILE - 1) / TILE;
  for (int tile = blockIdx.x; tile < ntiles; tile += gridDim.x) {
    const int base = tile * TILE;
    #pragma unroll
    for (int j = 0; j < TILE / 256; ++j) {
      const int e = base + j * 256 + t;   // coalesced
      if (e < E) {
        const int d = __builtin_nontemporal_load(&dst[e]);
        const int s = __builtin_nontemporal_load(&src[e]);
        const unsigned pw = ((unsigned)s << 10) | ((unsigned)d & 1023u);
        const int p = d >> 10;
        const int slot = atomicAdd(&lcnt[p], 1);
        if (slot < CAPA) lpk[p][slot] = pw;
        else ppack[atomicAdd(&curA[p], 1)] = pw;  // rare spill
      }
    }
    __syncthreads();
    if (t < NHB) {
      int c = lcnt[t]; if (c > CAPA) c = CAPA;
      lbase[t] = c ? atomicAdd(&curA[t], c) : 0;
      lcnt[t] = c;
    }
    __syncthreads();
    for (int p = 0; p < NHB; ++p) {
      const int c = lcnt[p];
      if (t < c) ppack[lbase[p] + t] = lpk[p][t];  // contiguous chunk
    }
    __syncthreads();
    if (t < NHB) lcnt[t] = 0;
    __syncthreads();
  }
}

// One workgroup (512 thr) per 512-node HALF-bucket. ALL threads participate
// in every phase (no predicated barriers). Filter parent ppack range by bit9
// of the low-10 dst bits; 512-bin LDS counting sort; 4-deep ILP.
// half-1 base = ehi - own_total (half-0 rows precede half-1 in dst order).
__global__ __launch_bounds__(512) void fillsort_kernel(
    const unsigned* __restrict__ ppack, const int* __restrict__ baseA,
    int* __restrict__ rowstart, int* __restrict__ csr, int N, int E) {
  __shared__ int hist[512];
  __shared__ int bs[512];
  const int t = threadIdx.x;          // 512
  const int hb = blockIdx.x;          // half-bucket id
  const int parent = hb >> 1;
  const unsigned half = (unsigned)(hb & 1);
  const int nlo = hb << 9;            // first node of this half
  const int elo = baseA[parent], ehi = baseA[parent + 1];

  hist[t] = 0;
  __syncthreads();

  // phase 1: histogram own half (4 independent loads in flight)
  int e = elo + t;
  for (; e + 3 * 512 < ehi; e += 4 * 512) {
    const unsigned p0 = ppack[e],           p1 = ppack[e + 512];
    const unsigned p2 = ppack[e + 2 * 512], p3 = ppack[e + 3 * 512];
    if (((p0 >> 9) & 1u) == half) atomicAdd(&hist[p0 & 511u], 1);
    if (((p1 >> 9) & 1u) == half) atomicAdd(&hist[p1 & 511u], 1);
    if (((p2 >> 9) & 1u) == half) atomicAdd(&hist[p2 & 511u], 1);
    if (((p3 >> 9) & 1u) == half) atomicAdd(&hist[p3 & 511u], 1);
  }
  for (; e < ehi; e += 512) {
    const unsigned p = ppack[e];
    if (((p >> 9) & 1u) == half) atomicAdd(&hist[p & 511u], 1);
  }
  __syncthreads();

  // exclusive scan over 512 bins (all 512 threads; 9 rounds)
  const int c = hist[t];
  bs[t] = c;
  __syncthreads();
  for (int off = 1; off < 512; off <<= 1) {
    const int v = (t >= off) ? bs[t - off] : 0;
    __syncthreads();
    bs[t] += v;
    __syncthreads();
  }
  const int excl = bs[t] - c;
  const int total = bs[511];
  const int halfbase = half ? (ehi - total) : elo;

  hist[t] = excl;                     // LDS cursor
  const int n0 = nlo + t;
  if (n0 < N) rowstart[n0] = halfbase + excl;
  if (hb == 0 && t == 0) rowstart[N] = E;
  __syncthreads();

  // phase 2: place own half (csr window ~32KB, single CU owner)
  e = elo + t;
  for (; e + 3 * 512 < ehi; e += 4 * 512) {
    const unsigned p0 = ppack[e],           p1 = ppack[e + 512];
    const unsigned p2 = ppack[e + 2 * 512], p3 = ppack[e + 3 * 512];
    if (((p0 >> 9) & 1u) == half)
      csr[halfbase + atomicAdd(&hist[p0 & 511u], 1)] = (int)(p0 >> 10);
    if (((p1 >> 9) & 1u) == half)
      csr[halfbase + atomicAdd(&hist[p1 & 511u], 1)] = (int)(p1 >> 10);
    if (((p2 >> 9) & 1u) == half)
      csr[halfbase + atomicAdd(&hist[p2 & 511u], 1)] = (int)(p2 >> 10);
    if (((p3 >> 9) & 1u) == half)
      csr[halfbase + atomicAdd(&hist[p3 & 511u], 1)] = (int)(p3 >> 10);
  }
  for (; e < ehi; e += 512) {
    const unsigned p = ppack[e];
    if (((p >> 9) & 1u) == half)
      csr[halfbase + atomicAdd(&hist[p & 511u], 1)] = (int)(p >> 10);
  }
}

// ------- gather64 (split-lane pair): agg[d] = relu(z[d] + b + sum z[src]) -------
// Wave = 2 nodes; half h serves node n0+h, lane owns features (2*il, 2*il+1).
// One ushort VMEM per j serves one edge of EACH half (0.5 instr/edge).
// Proven form (R22/R23) -- do not restructure.
__global__ __launch_bounds__(256) void gather64_kernel(
    const unsigned char* __restrict__ z, const float* __restrict__ b,
    const int* __restrict__ rowstart, const int* __restrict__ csr,
    float* __restrict__ agg, int N) {
  const int lane = threadIdx.x & 63;
  const int h    = lane >> 5;
  const int il   = lane & 31;
  const int f0   = il << 1;
  const int pair = blockIdx.x * (blockDim.x >> 6) + (threadIdx.x >> 6);
  const int n0 = pair << 1;
  if (n0 >= N) return;
  const int node = n0 + h;
  const bool hv = (node < N);
  const int start = hv ? rowstart[node] : 0;
  const int end   = hv ? rowstart[node + 1] : 0;
  const int deg   = end - start;
  const int degA = __builtin_amdgcn_readfirstlane(deg);
  const int degB = __builtin_amdgcn_readlane(deg, 32);
  const int maxdeg = degA > degB ? degA : degB;

  const unsigned char* zp = z + f0;
  const unsigned short sv =
      hv ? *(const unsigned short*)(zp + (size_t)node * 64) : (unsigned short)0;

  float a00 = 0.f, a01 = 0.f, a10 = 0.f, a11 = 0.f;
  for (int w0 = 0; w0 < maxdeg; w0 += 32) {
    const int ei = start + w0 + il;
    const int safe = (ei < end) ? ei : (end > start ? end - 1 : 0);
    const int cidx = csr[safe];
    const int rem = maxdeg - w0;
    const int nloc = rem < 32 ? rem : 32;
    int j0 = 0;
    for (; j0 + 16 <= nloc; j0 += 16) {
      int idx[16];
      #pragma unroll
      for (int j = 0; j < 16; ++j)
        idx[j] = __shfl(cidx, (h << 5) + j0 + j, 64);
      unsigned short hh[16];
      #pragma unroll
      for (int j = 0; j < 16; ++j)
        hh[j] = *(const unsigned short*)(zp + (size_t)(unsigned)idx[j] * 64u);
      #pragma unroll
      for (int j = 0; j < 16; ++j) {
        const unsigned short m = (w0 + j0 + j < deg) ? hh[j] : (unsigned short)0;
        const floatx2 v = fp8x2tof(m);
        if (j & 1) { a10 += v.x; a11 += v.y; }
        else       { a00 += v.x; a01 += v.y; }
      }
    }
    for (; j0 + 4 <= nloc; j0 += 4) {
      int idx[4];
      #pragma unroll
      for (int j = 0; j < 4; ++j)
        idx[j] = __shfl(cidx, (h << 5) + j0 + j, 64);
      unsigned short hh[4];
      #pragma unroll
      for (int j = 0; j < 4; ++j)
        hh[j] = *(const unsigned short*)(zp + (size_t)(unsigned)idx[j] * 64u);
      #pragma unroll
      for (int j = 0; j < 4; ++j) {
        const unsigned short m = (w0 + j0 + j < deg) ? hh[j] : (unsigned short)0;
        const floatx2 v = fp8x2tof(m);
        if (j & 1) { a10 += v.x; a11 += v.y; }
        else       { a00 += v.x; a01 += v.y; }
      }
    }
    for (; j0 < nloc; ++j0) {
      const int idx = __shfl(cidx, (h << 5) + j0, 64);
      const unsigned short hh =
          *(const unsigned short*)(zp + (size_t)(unsigned)idx * 64u);
      const unsigned short m = (w0 + j0 < deg) ? hh : (unsigned short)0;
      const floatx2 v = fp8x2tof(m);
      a00 += v.x; a01 += v.y;
    }
  }
  if (hv) {
    const floatx2 sf = fp8x2tof(sv);
    const float2 bb = *(const float2*)(b + f0);
    float2 st;
    st.x = fmaxf(sf.x + bb.x + a00 + a10, 0.f);
    st.y = fmaxf(sf.y + bb.y + a01 + a11, 0.f);
    *(float2*)(agg + (size_t)node * 64 + f0) = st;
  }
}

// ------- gather_l2 (split-lane pair): o = relu(sum z2' - (deg+1)*cm2 + b2) ------
// Structure IDENTICAL to gather64 (VGPR ~36, 0.5 instr/edge); o stored as
// bf16 pairs (packed uint per lane). W3 matvec moved to w3mat_kernel.
__global__ __launch_bounds__(256) void gather_l2_kernel(
    const unsigned char* __restrict__ z2, const float* __restrict__ b2,
    const float* __restrict__ cm2, const int* __restrict__ rowstart,
    const int* __restrict__ csr, unsigned* __restrict__ o, int N) {
  const int lane = threadIdx.x & 63;
  const int h    = lane >> 5;
  const int il   = lane & 31;
  const int f0   = il << 1;
  const int pair = blockIdx.x * (blockDim.x >> 6) + (threadIdx.x >> 6);
  const int n0 = pair << 1;
  if (n0 >= N) return;
  const int node = n0 + h;
  const bool hv = (node < N);
  const int start = hv ? rowstart[node] : 0;
  const int end   = hv ? rowstart[node + 1] : 0;
  const int deg   = end - start;
  const int degA = __builtin_amdgcn_readfirstlane(deg);
  const int degB = __builtin_amdgcn_readlane(deg, 32);
  const int maxdeg = degA > degB ? degA : degB;

  const unsigned char* zp = z2 + f0;
  const unsigned short sv =
      hv ? *(const unsigned short*)(zp + (size_t)node * 64) : (unsigned short)0;

  float a00 = 0.f, a01 = 0.f, a10 = 0.f, a11 = 0.f;
  for (int w0 = 0; w0 < maxdeg; w0 += 32) {
    const int ei = start + w0 + il;
    const int safe = (ei < end) ? ei : (end > start ? end - 1 : 0);
    const int cidx = csr[safe];
    const int rem = maxdeg - w0;
    const int nloc = rem < 32 ? rem : 32;
    int j0 = 0;
    for (; j0 + 16 <= nloc; j0 += 16) {
      int idx[16];
      #pragma unroll
      for (int j = 0; j < 16; ++j)
        idx[j] = __shfl(cidx, (h << 5) + j0 + j, 64);
      unsigned short hh[16];
      #pragma unroll
      for (int j = 0; j < 16; ++j)
        hh[j] = *(const unsigned short*)(zp + (size_t)(unsigned)idx[j] * 64u);
      #pragma unroll
      for (int j = 0; j < 16; ++j) {
        const unsigned short m = (w0 + j0 + j < deg) ? hh[j] : (unsigned short)0;
        const floatx2 v = fp8x2tof(m);
        if (j & 1) { a10 += v.x; a11 += v.y; }
        else       { a00 += v.x; a01 += v.y; }
      }
    }
    for (; j0 + 4 <= nloc; j0 += 4) {
      int idx[4];
      #pragma unroll
      for (int j = 0; j < 4; ++j)
        idx[j] = __shfl(cidx, (h << 5) + j0 + j, 64);
      unsigned short hh[4];
      #pragma unroll
      for (int j = 0; j < 4; ++j)
        hh[j] = *(const unsigned short*)(zp + (size_t)(unsigned)idx[j] * 64u);
      #pragma unroll
      for (int j = 0; j < 4; ++j) {
        const unsigned short m = (w0 + j0 + j < deg) ? hh[j] : (unsigned short)0;
        const floatx2 v = fp8x2tof(m);
        if (j & 1) { a10 += v.x; a11 += v.y; }
        else       { a00 += v.x; a01 += v.y; }
      }
    }
    for (; j0 < nloc; ++j0) {
      const int idx = __shfl(cidx, (h << 5) + j0, 64);
      const unsigned short hh =
          *(const unsigned short*)(zp + (size_t)(unsigned)idx * 64u);
      const unsigned short m = (w0 + j0 < deg) ? hh : (unsigned short)0;
      const floatx2 v = fp8x2tof(m);
      a00 += v.x; a01 += v.y;
    }
  }
  if (hv) {
    const floatx2 sf = fp8x2tof(sv);
    const float2 bb = *(const float2*)(b2 + f0);
    const float2 cc = *(const float2*)(cm2 + f0);
    const float dp1 = (float)(deg + 1);
    const float o0 = fmaxf(sf.x + bb.x + (a00 + a10) - dp1 * cc.x, 0.f);
    const float o1 = fmaxf(sf.y + bb.y + (a01 + a11) - dp1 * cc.y, 0.f);
    o[(size_t)node * 32 + il] =
        (unsigned)f2bf(o0) | ((unsigned)f2bf(o1) << 16);
  }
}

// ------- w3mat: z3 = o @ W3 (streaming; one wave per node) -------
// Lane owns W3 row `lane`; 16 partials o[lane]*W3[lane][m]; split-butterfly
// reduction; lane l<16 stores output column bitrev4(l) as fp8.
__global__ __launch_bounds__(256) void w3mat_kernel(
    const unsigned short* __restrict__ o16, const float* __restrict__ W3,
    unsigned char* __restrict__ z3, int N) {
  const int lane = threadIdx.x & 63;
  int node = blockIdx.x * (blockDim.x >> 6) + (threadIdx.x >> 6);
  if (node >= N) return;
  node = __builtin_amdgcn_readfirstlane(node);
  float4 w4[4];
  #pragma unroll
  for (int q = 0; q < 4; ++q)
    w4[q] = ((const float4*)(W3 + lane * 16))[q];
  const float o = bf2f(o16[(size_t)node * 64 + lane]);

  float p[16];
  #pragma unroll
  for (int q = 0; q < 4; ++q) {
    p[4 * q + 0] = o * w4[q].x;
    p[4 * q + 1] = o * w4[q].y;
    p[4 * q + 2] = o * w4[q].z;
    p[4 * q + 3] = o * w4[q].w;
  }
  {
    const bool up = (lane & 1);
    #pragma unroll
    for (int m = 0; m < 8; ++m) {
      const float mine = up ? p[m + 8] : p[m];
      const float give = up ? p[m] : p[m + 8];
      p[m] = mine + __shfl_xor(give, 1, 64);
    }
  }
  {
    const bool up = (lane & 2);
    #pragma unroll
    for (int m = 0; m < 4; ++m) {
      const float mine = up ? p[m + 4] : p[m];
      const float give = up ? p[m] : p[m + 4];
      p[m] = mine + __shfl_xor(give, 2, 64);
    }
  }
  {
    const bool up = (lane & 4);
    #pragma unroll
    for (int m = 0; m < 2; ++m) {
      const float mine = up ? p[m + 2] : p[m];
      const float give = up ? p[m] : p[m + 2];
      p[m] = mine + __shfl_xor(give, 4, 64);
    }
  }
  {
    const bool up = (lane & 8);
    const float mine = up ? p[1] : p[0];
    const float give = up ? p[0] : p[1];
    p[0] = mine + __shfl_xor(give, 8, 64);
  }
  p[0] += __shfl_xor(p[0], 16, 64);
  p[0] += __shfl_xor(p[0], 32, 64);

  if (lane < 16) {
    const int j = ((lane & 1) << 3) | ((lane & 2) << 1) |
                  ((lane & 4) >> 1) | ((lane & 8) >> 3);
    z3[(size_t)node * 16 + j] = f2fp8(p[0]);
  }
}

// ------- gather16: out[d] = z3[d] + b3 + sum z3[src]; 16 feat x 4 edge-groups -------
__global__ __launch_bounds__(256) void gather16_kernel(
    const unsigned char* __restrict__ z3, const float* __restrict__ b3,
    const int* __restrict__ rowstart, const int* __restrict__ csr,
    float* __restrict__ out, int N) {
  const int lane = threadIdx.x & 63;
  const int f = lane & 15;
  const int g = lane >> 4;
  int node = blockIdx.x * (blockDim.x >> 6) + (threadIdx.x >> 6);
  if (node >= N) return;
  node = __builtin_amdgcn_readfirstlane(node);
  const int start = rowstart[node];
  const int end   = rowstart[node + 1];
  float acc0 = 0.f, acc1 = 0.f;
  int e = start + g;
  for (; e + 4 < end; e += 8) {
    acc0 += fp8tof(z3[(size_t)csr[e] * 16 + f]);
    acc1 += fp8tof(z3[(size_t)csr[e + 4] * 16 + f]);
  }
  if (e < end) acc0 += fp8tof(z3[(size_t)csr[e] * 16 + f]);
  float acc = acc0 + acc1;
  acc += __shfl_xor(acc, 16, 64);
  acc += __shfl_xor(acc, 32, 64);
  if (lane < 16)
    out[(size_t)node * 16 + f] = fp8tof(z3[(size_t)node * 16 + f]) + b3[f] + acc;
}

extern "C" void kernel_launch(void* const* d_in, const int* in_sizes, int n_in,
                              void* d_out, int out_size, void* d_ws, size_t ws_size,
                              hipStream_t stream) {
  const float* feat = (const float*)d_in[0];
  const float* W1 = (const float*)d_in[1];
  const float* b1 = (const float*)d_in[2];
  const float* W2 = (const float*)d_in[3];
  const float* b2 = (const float*)d_in[4];
  const float* W3 = (const float*)d_in[5];
  const float* b3 = (const float*)d_in[6];
  const int* src = (const int*)d_in[7];
  const int* dst = (const int*)d_in[8];
  const int N = in_sizes[0] / 64;
  const int E = in_sizes[7];
  float* out = (float*)d_out;

  // workspace layout
  float* B            = (float*)d_ws;                     // agg1, N*64 fp32
  unsigned char* zb   = (unsigned char*)(B + (size_t)N * 64);   // z1/z2' fp8 N*64
  unsigned char* z3b  = zb + (size_t)N * 64;              // z3, N*16 fp8
  int* cntA  = (int*)(z3b + (size_t)N * 16);              // NHB  } one memset
  float* cs1 = (float*)(cntA + NHB);                      // 64   } covers
  float* cs2 = cs1 + 64;                                  // 64   } these 3
  float* cm2w = cs2 + 64;                                 // 64 (no memset needed)
  int* baseA    = (int*)(cm2w + 64);                      // NHB+1
  int* curA     = baseA + NHB + 1;                        // NHB
  int* rowstart = curA + NHB;                             // N+1
  int* csr      = rowstart + N + 1;                       // E
  // ppack aliases zb+z3b (dead until matnorm1 writes zb, after fillsort)
  unsigned* ppack = (unsigned*)zb;
  // o (bf16 N*64 = N*32 uints) aliases B (dead after matnorm2 reads it)
  unsigned* ob = (unsigned*)B;

  const int NHI = (N + 1023) >> 10;     // 98
  const int node_blocks = (N + 3) / 4;  // 4 waves of 64 per block
  const int npairs = (N + 1) / 2;
  const int pair_blocks = (npairs + 3) / 4;  // 4 pair-waves per block
  const float invN = 1.0f / (float)N;

  // ---- CSR build + layer-1 colsum ----
  hipMemsetAsync(cntA, 0, (NHB + 128) * sizeof(int), stream);  // cntA+cs1+cs2
  prelude_kernel<<<512, 256, 0, stream>>>(dst, cntA, E, feat, cs1, N * 16);
  scanA_kernel<<<1, NHB, 0, stream>>>(cntA, baseA, curA, NHI);
  scatterA_kernel<<<512, 256, 0, stream>>>(src, dst, curA, ppack, E);
  fillsort_kernel<<<2 * NHI, 512, 0, stream>>>(ppack, baseA, rowstart, csr, N, E);

  // ---- layer 1 (split-lane pair gather) ----
  matnorm_kernel<<<2048, 256, 0, stream>>>(feat, W1, cs1, zb, N, invN);
  gather64_kernel<<<pair_blocks, 256, 0, stream>>>(zb, b1, rowstart, csr, B, N);

  // ---- layer 2: matnorm2 emits UNcentered z2' and accumulates cs2 itself ----
  matnorm2_kernel<<<2048, 256, 0, stream>>>(B, W2, cs2, zb, N);
  cm2_kernel<<<1, 64, 0, stream>>>(cs2, W2, cm2w, invN);
  gather_l2_kernel<<<pair_blocks, 256, 0, stream>>>(zb, b2, cm2w, rowstart, csr,
                                                    ob, N);
  w3mat_kernel<<<node_blocks, 256, 0, stream>>>((const unsigned short*)ob, W3,
                                                z3b, N);

  // ---- layer 3 final aggregation ----
  gather16_kernel<<<node_blocks, 256, 0, stream>>>(z3b, b3, rowstart, csr, out, N);
}

// Round 19
// 361.906 us; speedup vs baseline: 1.0425x; 1.0425x over previous
//
#include <hip/hip_runtime.h>
#include <hip/hip_fp8.h>

// GCN: N=100000 nodes, E=1600000 edges, F_IN=F_HID=64, F_OUT=16, fp32.
//
// R31 -> R32: REVERT to the measured-best R29/R30 source (360.7us).
// R31's matnorm grid 1024->2048 REGRESSED (matnorm2 48->66us, occ only
// 32%, VALU down): the kernel is PREAMBLE-dominated (fixed ~64-load W
// staging per wave); doubling waves halves rows/wave so the preamble
// amortizes half as well -- same cost-family lesson as R20's grid-stride
// gather64. 1024 blocks is the proven point. Final configuration:
//  - CSR: prelude + scanA + scatterA + half-bucket fillsort (512 thr)
//  - L1: matnorm1 (fp8 z1) + split-lane pair gather64 (0.5 instr/edge)
//  - L2: matnorm2 (UNcentered z2', fused colsum) + cm2 + split-lane
//        gather_l2 (bf16 o) + streaming w3mat (fp8 z3)
//  - L3: gather16
// Known walls (measured): gather_l2/64 at the L2 random-line request rate
// (~24K lines/us); matnorm at its preamble+chain point (~48us); total
// bounded by 10 latency/issue-bound kernels, not bandwidth.

#define NHB 128     // max hi-buckets of 1024 nodes (N <= 131072); hi = dst >> 10

typedef float floatx2 __attribute__((ext_vector_type(2)));

__device__ __forceinline__ unsigned short f2bf(float f) {
  unsigned u = __builtin_bit_cast(unsigned, f);
  u += 0x7FFFu + ((u >> 16) & 1u);    // round-to-nearest-even
  return (unsigned short)(u >> 16);
}
__device__ __forceinline__ float bf2f(unsigned short h) {
  return __builtin_bit_cast(float, ((unsigned)h) << 16);
}
__device__ __forceinline__ float rlane(float v, int k) {
  return __builtin_bit_cast(
      float, __builtin_amdgcn_readlane(__builtin_bit_cast(int, v), k));
}
__device__ __forceinline__ unsigned char f2fp8(float f) {
  __hip_fp8_e4m3 t(f);                // RNE, saturate-to-finite (OCP)
  return (unsigned char)t.__x;
}
// hardware OCP e4m3 -> f32 (gfx950); exact fallback via f16-embedding.
__device__ __forceinline__ float fp8tof(unsigned v) {
#if __has_builtin(__builtin_amdgcn_cvt_f32_fp8)
  return __builtin_amdgcn_cvt_f32_fp8((int)v, 0);
#else
  const unsigned h = ((v << 8) & 0x8000u) | ((v << 7) & 0x3f80u);
  __half_raw hr; hr.x = (unsigned short)h;
  return (float)__half(hr) * 256.0f;
#endif
}
// packed pair decode: 2 fp8 bytes -> 2 floats in one instruction
__device__ __forceinline__ floatx2 fp8x2tof(unsigned short p) {
#if __has_builtin(__builtin_amdgcn_cvt_pk_f32_fp8)
  return __builtin_amdgcn_cvt_pk_f32_fp8((int)(unsigned)p, false);
#else
  floatx2 r; r.x = fp8tof(p & 0xffu); r.y = fp8tof(p >> 8); return r;
#endif
}

// ------- prelude: cntA histogram of dst (hi-buckets) + column sums of feat -------
__global__ __launch_bounds__(256) void prelude_kernel(
    const int* __restrict__ dst, int* __restrict__ cntA, int E,
    const float* __restrict__ x, float* __restrict__ cs, int n4) {
  __shared__ int lc[NHB];
  __shared__ float lds[16][64];
  const int t = threadIdx.x;
  if (t < NHB) lc[t] = 0;
  __syncthreads();
  const int stride = gridDim.x * blockDim.x;
  for (int e = blockIdx.x * blockDim.x + t; e < E; e += stride)
    atomicAdd(&lc[__builtin_nontemporal_load(&dst[e]) >> 10], 1);

  float s0 = 0.f, s1 = 0.f, s2 = 0.f, s3 = 0.f;
  for (int i = blockIdx.x * blockDim.x + t; i < n4; i += stride) {
    float4 v = ((const float4*)x)[i];
    s0 += v.x; s1 += v.y; s2 += v.z; s3 += v.w;
  }
  const int r = t >> 4;
  const int cq = (t & 15) * 4;
  lds[r][cq + 0] = s0; lds[r][cq + 1] = s1; lds[r][cq + 2] = s2; lds[r][cq + 3] = s3;
  __syncthreads();
  if (t < NHB && lc[t]) atomicAdd(&cntA[t], lc[t]);
  if (t < 64) {
    float tot = 0.f;
    #pragma unroll
    for (int rr = 0; rr < 16; ++rr) tot += lds[rr][t];
    unsafeAtomicAdd(&cs[t], tot);
  }
}

// ------- layer1: z = (x @ W) * rinv - cm, fp8 out; 4-chain FMA -------
__global__ __launch_bounds__(256) void matnorm_kernel(
    const float* x, const float* __restrict__ W,
    const float* __restrict__ cs, unsigned char* __restrict__ z,
    int N, float invN) {
  const int lane = threadIdx.x & 63;
  const int wid  = blockIdx.x * (blockDim.x >> 6) + (threadIdx.x >> 6);
  const int nw   = gridDim.x * (blockDim.x >> 6);

  float w[64];
  float cm0 = 0.f, cm1 = 0.f, cm2 = 0.f, cm3 = 0.f;
  #pragma unroll
  for (int k = 0; k < 64; k += 4) {
    w[k + 0] = W[(k + 0) * 64 + lane];
    w[k + 1] = W[(k + 1) * 64 + lane];
    w[k + 2] = W[(k + 2) * 64 + lane];
    w[k + 3] = W[(k + 3) * 64 + lane];
    cm0 = fmaf(cs[k + 0], w[k + 0], cm0);
    cm1 = fmaf(cs[k + 1], w[k + 1], cm1);
    cm2 = fmaf(cs[k + 2], w[k + 2], cm2);
    cm3 = fmaf(cs[k + 3], w[k + 3], cm3);
  }
  const float cm = ((cm0 + cm1) + (cm2 + cm3)) * invN;

  for (int row = wid; row < N; row += nw) {
    const float xv = x[(size_t)row * 64 + lane];
    float ss = xv * xv;
    #pragma unroll
    for (int m = 1; m < 64; m <<= 1) ss += __shfl_xor(ss, m, 64);
    const float rinv = 1.0f / sqrtf(1e-6f + ss);
    float a0 = 0.f, a1 = 0.f, a2 = 0.f, a3 = 0.f;
    #pragma unroll
    for (int k = 0; k < 64; k += 4) {
      a0 = fmaf(rlane(xv, k + 0), w[k + 0], a0);
      a1 = fmaf(rlane(xv, k + 1), w[k + 1], a1);
      a2 = fmaf(rlane(xv, k + 2), w[k + 2], a2);
      a3 = fmaf(rlane(xv, k + 3), w[k + 3], a3);
    }
    const float acc = (a0 + a1) + (a2 + a3);
    z[(size_t)row * 64 + lane] = f2fp8(acc * rinv - cm);
  }
}

// ------- layer2: z2' = (x @ W) * rinv (UNcentered), fp8 out; cs += colsum(x) -------
__global__ __launch_bounds__(256) void matnorm2_kernel(
    const float* x, const float* __restrict__ W,
    float* __restrict__ cs, unsigned char* __restrict__ z, int N) {
  __shared__ float lred[4][64];
  const int lane = threadIdx.x & 63;
  const int wv   = threadIdx.x >> 6;
  const int wid  = blockIdx.x * (blockDim.x >> 6) + wv;
  const int nw   = gridDim.x * (blockDim.x >> 6);

  float w[64];
  #pragma unroll
  for (int k = 0; k < 64; k += 4) {
    w[k + 0] = W[(k + 0) * 64 + lane];
    w[k + 1] = W[(k + 1) * 64 + lane];
    w[k + 2] = W[(k + 2) * 64 + lane];
    w[k + 3] = W[(k + 3) * 64 + lane];
  }

  float csum = 0.f;
  for (int row = wid; row < N; row += nw) {
    const float xv = x[(size_t)row * 64 + lane];
    csum += xv;
    float ss = xv * xv;
    #pragma unroll
    for (int m = 1; m < 64; m <<= 1) ss += __shfl_xor(ss, m, 64);
    const float rinv = 1.0f / sqrtf(1e-6f + ss);
    float a0 = 0.f, a1 = 0.f, a2 = 0.f, a3 = 0.f;
    #pragma unroll
    for (int k = 0; k < 64; k += 4) {
      a0 = fmaf(rlane(xv, k + 0), w[k + 0], a0);
      a1 = fmaf(rlane(xv, k + 1), w[k + 1], a1);
      a2 = fmaf(rlane(xv, k + 2), w[k + 2], a2);
      a3 = fmaf(rlane(xv, k + 3), w[k + 3], a3);
    }
    const float acc = (a0 + a1) + (a2 + a3);
    z[(size_t)row * 64 + lane] = f2fp8(acc * rinv);
  }
  lred[wv][lane] = csum;
  __syncthreads();
  if (threadIdx.x < 64) {
    const float tot = lred[0][lane] + lred[1][lane] + lred[2][lane] + lred[3][lane];
    unsafeAtomicAdd(&cs[lane], tot);
  }
}

// ------- cm2[m] = invN * sum_k cs2[k] * W2[k][m]  (1 wave) -------
__global__ void cm2_kernel(const float* __restrict__ cs,
                           const float* __restrict__ W,
                           float* __restrict__ cm2, float invN) {
  const int m = threadIdx.x;   // 64
  float a0 = 0.f, a1 = 0.f, a2 = 0.f, a3 = 0.f;
  #pragma unroll
  for (int k = 0; k < 64; k += 4) {
    a0 = fmaf(cs[k + 0], W[(k + 0) * 64 + m], a0);
    a1 = fmaf(cs[k + 1], W[(k + 1) * 64 + m], a1);
    a2 = fmaf(cs[k + 2], W[(k + 2) * 64 + m], a2);
    a3 = fmaf(cs[k + 3], W[(k + 3) * 64 + m], a3);
  }
  cm2[m] = ((a0 + a1) + (a2 + a3)) * invN;
}

// ================= CSR build: hi-bucket radix + LDS counting sort =================
// Edge packed as (src << 10) | (dst & 1023): src < 2^17 -> 27 bits used.

// 128-thread LDS Hillis-Steele exclusive scan over the hi-bucket counts.
__global__ void scanA_kernel(const int* __restrict__ cntA,
                             int* __restrict__ baseA, int* __restrict__ curA,
                             int NHI) {
  __shared__ int s[NHB];
  const int t = threadIdx.x;   // 128
  const int v = (t < NHI) ? cntA[t] : 0;
  s[t] = v;
  __syncthreads();
  int acc = v;
  for (int off = 1; off < NHB; off <<= 1) {
    const int add = (t >= off) ? s[t - off] : 0;
    __syncthreads();
    acc += add;
    s[t] = acc;
    __syncthreads();
  }
  const int excl = acc - v;
  if (t < NHI) { baseA[t] = excl; curA[t] = excl; }
  if (t == NHI - 1) baseA[NHI] = acc;
}

#define TILE 2048
#define CAPA 48   // per-tile per-bucket mean 21, sigma 4.6 -> ~6 sigma + spill
__global__ __launch_bounds__(256) void scatterA_kernel(
    const int* __restrict__ src, const int* __restrict__ dst,
    int* __restrict__ curA, unsigned* __restrict__ ppack, int E) {
  __shared__ unsigned lpk[NHB][CAPA];
  __shared__ int lcnt[NHB], lbase[NHB];
  const int t = threadIdx.x;
  if (t < NHB) lcnt[t] = 0;
  __syncthreads();
  const int ntiles = (E + TILE - 1) / TILE;
  for (int tile = blockIdx.x; tile < ntiles; tile += gridDim.x) {
    const int base = tile * TILE;
    #pragma unroll
    for (int j = 0; j < TILE / 256; ++j) {
      const int e = base + j * 256 + t;   // coalesced
      if (e < E) {
        const int d = __builtin_nontemporal_load(&dst[e]);
        const int s = __builtin_nontemporal_load(&src[e]);
        const unsigned pw = ((unsigned)s << 10) | ((unsigned)d & 1023u);
        const int p = d >> 10;
        const int slot = atomicAdd(&lcnt[p], 1);
        if (slot < CAPA) lpk[p][slot] = pw;
        else ppack[atomicAdd(&curA[p], 1)] = pw;  // rare spill
      }
    }
    __syncthreads();
    if (t < NHB) {
      int c = lcnt[t]; if (c > CAPA) c = CAPA;
      lbase[t] = c ? atomicAdd(&curA[t], c) : 0;
      lcnt[t] = c;
    }
    __syncthreads();
    for (int p = 0; p < NHB; ++p) {
      const int c = lcnt[p];
      if (t < c) ppack[lbase[p] + t] = lpk[p][t];  // contiguous chunk
    }
    __syncthreads();
    if (t < NHB) lcnt[t] = 0;
    __syncthreads();
  }
}

// One workgroup (512 thr) per 512-node HALF-bucket. ALL threads participate
// in every phase (no predicated barriers). Filter parent ppack range by bit9
// of the low-10 dst bits; 512-bin LDS counting sort; 4-deep ILP.
// half-1 base = ehi - own_total (half-0 rows precede half-1 in dst order).
__global__ __launch_bounds__(512) void fillsort_kernel(
    const unsigned* __restrict__ ppack, const int* __restrict__ baseA,
    int* __restrict__ rowstart, int* __restrict__ csr, int N, int E) {
  __shared__ int hist[512];
  __shared__ int bs[512];
  const int t = threadIdx.x;          // 512
  const int hb = blockIdx.x;          // half-bucket id
  const int parent = hb >> 1;
  const unsigned half = (unsigned)(hb & 1);
  const int nlo = hb << 9;            // first node of this half
  const int elo = baseA[parent], ehi = baseA[parent + 1];

  hist[t] = 0;
  __syncthreads();

  // phase 1: histogram own half (4 independent loads in flight)
  int e = elo + t;
  for (; e + 3 * 512 < ehi; e += 4 * 512) {
    const unsigned p0 = ppack[e],           p1 = ppack[e + 512];
    const unsigned p2 = ppack[e + 2 * 512], p3 = ppack[e + 3 * 512];
    if (((p0 >> 9) & 1u) == half) atomicAdd(&hist[p0 & 511u], 1);
    if (((p1 >> 9) & 1u) == half) atomicAdd(&hist[p1 & 511u], 1);
    if (((p2 >> 9) & 1u) == half) atomicAdd(&hist[p2 & 511u], 1);
    if (((p3 >> 9) & 1u) == half) atomicAdd(&hist[p3 & 511u], 1);
  }
  for (; e < ehi; e += 512) {
    const unsigned p = ppack[e];
    if (((p >> 9) & 1u) == half) atomicAdd(&hist[p & 511u], 1);
  }
  __syncthreads();

  // exclusive scan over 512 bins (all 512 threads; 9 rounds)
  const int c = hist[t];
  bs[t] = c;
  __syncthreads();
  for (int off = 1; off < 512; off <<= 1) {
    const int v = (t >= off) ? bs[t - off] : 0;
    __syncthreads();
    bs[t] += v;
    __syncthreads();
  }
  const int excl = bs[t] - c;
  const int total = bs[511];
  const int halfbase = half ? (ehi - total) : elo;

  hist[t] = excl;                     // LDS cursor
  const int n0 = nlo + t;
  if (n0 < N) rowstart[n0] = halfbase + excl;
  if (hb == 0 && t == 0) rowstart[N] = E;
  __syncthreads();

  // phase 2: place own half (csr window ~32KB, single CU owner)
  e = elo + t;
  for (; e + 3 * 512 < ehi; e += 4 * 512) {
    const unsigned p0 = ppack[e],           p1 = ppack[e + 512];
    const unsigned p2 = ppack[e + 2 * 512], p3 = ppack[e + 3 * 512];
    if (((p0 >> 9) & 1u) == half)
      csr[halfbase + atomicAdd(&hist[p0 & 511u], 1)] = (int)(p0 >> 10);
    if (((p1 >> 9) & 1u) == half)
      csr[halfbase + atomicAdd(&hist[p1 & 511u], 1)] = (int)(p1 >> 10);
    if (((p2 >> 9) & 1u) == half)
      csr[halfbase + atomicAdd(&hist[p2 & 511u], 1)] = (int)(p2 >> 10);
    if (((p3 >> 9) & 1u) == half)
      csr[halfbase + atomicAdd(&hist[p3 & 511u], 1)] = (int)(p3 >> 10);
  }
  for (; e < ehi; e += 512) {
    const unsigned p = ppack[e];
    if (((p >> 9) & 1u) == half)
      csr[halfbase + atomicAdd(&hist[p & 511u], 1)] = (int)(p >> 10);
  }
}

// ------- gather64 (split-lane pair): agg[d] = relu(z[d] + b + sum z[src]) -------
// Wave = 2 nodes; half h serves node n0+h, lane owns features (2*il, 2*il+1).
// One ushort VMEM per j serves one edge of EACH half (0.5 instr/edge).
// Proven form (R22/R23) -- do not restructure.
__global__ __launch_bounds__(256) void gather64_kernel(
    const unsigned char* __restrict__ z, const float* __restrict__ b,
    const int* __restrict__ rowstart, const int* __restrict__ csr,
    float* __restrict__ agg, int N) {
  const int lane = threadIdx.x & 63;
  const int h    = lane >> 5;
  const int il   = lane & 31;
  const int f0   = il << 1;
  const int pair = blockIdx.x * (blockDim.x >> 6) + (threadIdx.x >> 6);
  const int n0 = pair << 1;
  if (n0 >= N) return;
  const int node = n0 + h;
  const bool hv = (node < N);
  const int start = hv ? rowstart[node] : 0;
  const int end   = hv ? rowstart[node + 1] : 0;
  const int deg   = end - start;
  const int degA = __builtin_amdgcn_readfirstlane(deg);
  const int degB = __builtin_amdgcn_readlane(deg, 32);
  const int maxdeg = degA > degB ? degA : degB;

  const unsigned char* zp = z + f0;
  const unsigned short sv =
      hv ? *(const unsigned short*)(zp + (size_t)node * 64) : (unsigned short)0;

  float a00 = 0.f, a01 = 0.f, a10 = 0.f, a11 = 0.f;
  for (int w0 = 0; w0 < maxdeg; w0 += 32) {
    const int ei = start + w0 + il;
    const int safe = (ei < end) ? ei : (end > start ? end - 1 : 0);
    const int cidx = csr[safe];
    const int rem = maxdeg - w0;
    const int nloc = rem < 32 ? rem : 32;
    int j0 = 0;
    for (; j0 + 16 <= nloc; j0 += 16) {
      int idx[16];
      #pragma unroll
      for (int j = 0; j < 16; ++j)
        idx[j] = __shfl(cidx, (h << 5) + j0 + j, 64);
      unsigned short hh[16];
      #pragma unroll
      for (int j = 0; j < 16; ++j)
        hh[j] = *(const unsigned short*)(zp + (size_t)(unsigned)idx[j] * 64u);
      #pragma unroll
      for (int j = 0; j < 16; ++j) {
        const unsigned short m = (w0 + j0 + j < deg) ? hh[j] : (unsigned short)0;
        const floatx2 v = fp8x2tof(m);
        if (j & 1) { a10 += v.x; a11 += v.y; }
        else       { a00 += v.x; a01 += v.y; }
      }
    }
    for (; j0 + 4 <= nloc; j0 += 4) {
      int idx[4];
      #pragma unroll
      for (int j = 0; j < 4; ++j)
        idx[j] = __shfl(cidx, (h << 5) + j0 + j, 64);
      unsigned short hh[4];
      #pragma unroll
      for (int j = 0; j < 4; ++j)
        hh[j] = *(const unsigned short*)(zp + (size_t)(unsigned)idx[j] * 64u);
      #pragma unroll
      for (int j = 0; j < 4; ++j) {
        const unsigned short m = (w0 + j0 + j < deg) ? hh[j] : (unsigned short)0;
        const floatx2 v = fp8x2tof(m);
        if (j & 1) { a10 += v.x; a11 += v.y; }
        else       { a00 += v.x; a01 += v.y; }
      }
    }
    for (; j0 < nloc; ++j0) {
      const int idx = __shfl(cidx, (h << 5) + j0, 64);
      const unsigned short hh =
          *(const unsigned short*)(zp + (size_t)(unsigned)idx * 64u);
      const unsigned short m = (w0 + j0 < deg) ? hh : (unsigned short)0;
      const floatx2 v = fp8x2tof(m);
      a00 += v.x; a01 += v.y;
    }
  }
  if (hv) {
    const floatx2 sf = fp8x2tof(sv);
    const float2 bb = *(const float2*)(b + f0);
    float2 st;
    st.x = fmaxf(sf.x + bb.x + a00 + a10, 0.f);
    st.y = fmaxf(sf.y + bb.y + a01 + a11, 0.f);
    *(float2*)(agg + (size_t)node * 64 + f0) = st;
  }
}

// ------- gather_l2 (split-lane pair): o = relu(sum z2' - (deg+1)*cm2 + b2) ------
// Structure IDENTICAL to gather64 (VGPR ~36, 0.5 instr/edge); o stored as
// bf16 pairs (packed uint per lane). W3 matvec moved to w3mat_kernel.
__global__ __launch_bounds__(256) void gather_l2_kernel(
    const unsigned char* __restrict__ z2, const float* __restrict__ b2,
    const float* __restrict__ cm2, const int* __restrict__ rowstart,
    const int* __restrict__ csr, unsigned* __restrict__ o, int N) {
  const int lane = threadIdx.x & 63;
  const int h    = lane >> 5;
  const int il   = lane & 31;
  const int f0   = il << 1;
  const int pair = blockIdx.x * (blockDim.x >> 6) + (threadIdx.x >> 6);
  const int n0 = pair << 1;
  if (n0 >= N) return;
  const int node = n0 + h;
  const bool hv = (node < N);
  const int start = hv ? rowstart[node] : 0;
  const int end   = hv ? rowstart[node + 1] : 0;
  const int deg   = end - start;
  const int degA = __builtin_amdgcn_readfirstlane(deg);
  const int degB = __builtin_amdgcn_readlane(deg, 32);
  const int maxdeg = degA > degB ? degA : degB;

  const unsigned char* zp = z2 + f0;
  const unsigned short sv =
      hv ? *(const unsigned short*)(zp + (size_t)node * 64) : (unsigned short)0;

  float a00 = 0.f, a01 = 0.f, a10 = 0.f, a11 = 0.f;
  for (int w0 = 0; w0 < maxdeg; w0 += 32) {
    const int ei = start + w0 + il;
    const int safe = (ei < end) ? ei : (end > start ? end - 1 : 0);
    const int cidx = csr[safe];
    const int rem = maxdeg - w0;
    const int nloc = rem < 32 ? rem : 32;
    int j0 = 0;
    for (; j0 + 16 <= nloc; j0 += 16) {
      int idx[16];
      #pragma unroll
      for (int j = 0; j < 16; ++j)
        idx[j] = __shfl(cidx, (h << 5) + j0 + j, 64);
      unsigned short hh[16];
      #pragma unroll
      for (int j = 0; j < 16; ++j)
        hh[j] = *(const unsigned short*)(zp + (size_t)(unsigned)idx[j] * 64u);
      #pragma unroll
      for (int j = 0; j < 16; ++j) {
        const unsigned short m = (w0 + j0 + j < deg) ? hh[j] : (unsigned short)0;
        const floatx2 v = fp8x2tof(m);
        if (j & 1) { a10 += v.x; a11 += v.y; }
        else       { a00 += v.x; a01 += v.y; }
      }
    }
    for (; j0 + 4 <= nloc; j0 += 4) {
      int idx[4];
      #pragma unroll
      for (int j = 0; j < 4; ++j)
        idx[j] = __shfl(cidx, (h << 5) + j0 + j, 64);
      unsigned short hh[4];
      #pragma unroll
      for (int j = 0; j < 4; ++j)
        hh[j] = *(const unsigned short*)(zp + (size_t)(unsigned)idx[j] * 64u);
      #pragma unroll
      for (int j = 0; j < 4; ++j) {
        const unsigned short m = (w0 + j0 + j < deg) ? hh[j] : (unsigned short)0;
        const floatx2 v = fp8x2tof(m);
        if (j & 1) { a10 += v.x; a11 += v.y; }
        else       { a00 += v.x; a01 += v.y; }
      }
    }
    for (; j0 < nloc; ++j0) {
      const int idx = __shfl(cidx, (h << 5) + j0, 64);
      const unsigned short hh =
          *(const unsigned short*)(zp + (size_t)(unsigned)idx * 64u);
      const unsigned short m = (w0 + j0 < deg) ? hh : (unsigned short)0;
      const floatx2 v = fp8x2tof(m);
      a00 += v.x; a01 += v.y;
    }
  }
  if (hv) {
    const floatx2 sf = fp8x2tof(sv);
    const float2 bb = *(const float2*)(b2 + f0);
    const float2 cc = *(const float2*)(cm2 + f0);
    const float dp1 = (float)(deg + 1);
    const float o0 = fmaxf(sf.x + bb.x + (a00 + a10) - dp1 * cc.x, 0.f);
    const float o1 = fmaxf(sf.y + bb.y + (a01 + a11) - dp1 * cc.y, 0.f);
    o[(size_t)node * 32 + il] =
        (unsigned)f2bf(o0) | ((unsigned)f2bf(o1) << 16);
  }
}

// ------- w3mat: z3 = o @ W3 (streaming; one wave per node) -------
// Lane owns W3 row `lane`; 16 partials o[lane]*W3[lane][m]; split-butterfly
// reduction; lane l<16 stores output column bitrev4(l) as fp8.
__global__ __launch_bounds__(256) void w3mat_kernel(
    const unsigned short* __restrict__ o16, const float* __restrict__ W3,
    unsigned char* __restrict__ z3, int N) {
  const int lane = threadIdx.x & 63;
  int node = blockIdx.x * (blockDim.x >> 6) + (threadIdx.x >> 6);
  if (node >= N) return;
  node = __builtin_amdgcn_readfirstlane(node);
  float4 w4[4];
  #pragma unroll
  for (int q = 0; q < 4; ++q)
    w4[q] = ((const float4*)(W3 + lane * 16))[q];
  const float o = bf2f(o16[(size_t)node * 64 + lane]);

  float p[16];
  #pragma unroll
  for (int q = 0; q < 4; ++q) {
    p[4 * q + 0] = o * w4[q].x;
    p[4 * q + 1] = o * w4[q].y;
    p[4 * q + 2] = o * w4[q].z;
    p[4 * q + 3] = o * w4[q].w;
  }
  {
    const bool up = (lane & 1);
    #pragma unroll
    for (int m = 0; m < 8; ++m) {
      const float mine = up ? p[m + 8] : p[m];
      const float give = up ? p[m] : p[m + 8];
      p[m] = mine + __shfl_xor(give, 1, 64);
    }
  }
  {
    const bool up = (lane & 2);
    #pragma unroll
    for (int m = 0; m < 4; ++m) {
      const float mine = up ? p[m + 4] : p[m];
      const float give = up ? p[m] : p[m + 4];
      p[m] = mine + __shfl_xor(give, 2, 64);
    }
  }
  {
    const bool up = (lane & 4);
    #pragma unroll
    for (int m = 0; m < 2; ++m) {
      const float mine = up ? p[m + 2] : p[m];
      const float give = up ? p[m] : p[m + 2];
      p[m] = mine + __shfl_xor(give, 4, 64);
    }
  }
  {
    const bool up = (lane & 8);
    const float mine = up ? p[1] : p[0];
    const float give = up ? p[0] : p[1];
    p[0] = mine + __shfl_xor(give, 8, 64);
  }
  p[0] += __shfl_xor(p[0], 16, 64);
  p[0] += __shfl_xor(p[0], 32, 64);

  if (lane < 16) {
    const int j = ((lane & 1) << 3) | ((lane & 2) << 1) |
                  ((lane & 4) >> 1) | ((lane & 8) >> 3);
    z3[(size_t)node * 16 + j] = f2fp8(p[0]);
  }
}

// ------- gather16: out[d] = z3[d] + b3 + sum z3[src]; 16 feat x 4 edge-groups -------
__global__ __launch_bounds__(256) void gather16_kernel(
    const unsigned char* __restrict__ z3, const float* __restrict__ b3,
    const int* __restrict__ rowstart, const int* __restrict__ csr,
    float* __restrict__ out, int N) {
  const int lane = threadIdx.x & 63;
  const int f = lane & 15;
  const int g = lane >> 4;
  int node = blockIdx.x * (blockDim.x >> 6) + (threadIdx.x >> 6);
  if (node >= N) return;
  node = __builtin_amdgcn_readfirstlane(node);
  const int start = rowstart[node];
  const int end   = rowstart[node + 1];
  float acc0 = 0.f, acc1 = 0.f;
  int e = start + g;
  for (; e + 4 < end; e += 8) {
    acc0 += fp8tof(z3[(size_t)csr[e] * 16 + f]);
    acc1 += fp8tof(z3[(size_t)csr[e + 4] * 16 + f]);
  }
  if (e < end) acc0 += fp8tof(z3[(size_t)csr[e] * 16 + f]);
  float acc = acc0 + acc1;
  acc += __shfl_xor(acc, 16, 64);
  acc += __shfl_xor(acc, 32, 64);
  if (lane < 16)
    out[(size_t)node * 16 + f] = fp8tof(z3[(size_t)node * 16 + f]) + b3[f] + acc;
}

extern "C" void kernel_launch(void* const* d_in, const int* in_sizes, int n_in,
                              void* d_out, int out_size, void* d_ws, size_t ws_size,
                              hipStream_t stream) {
  const float* feat = (const float*)d_in[0];
  const float* W1 = (const float*)d_in[1];
  const float* b1 = (const float*)d_in[2];
  const float* W2 = (const float*)d_in[3];
  const float* b2 = (const float*)d_in[4];
  const float* W3 = (const float*)d_in[5];
  const float* b3 = (const float*)d_in[6];
  const int* src = (const int*)d_in[7];
  const int* dst = (const int*)d_in[8];
  const int N = in_sizes[0] / 64;
  const int E = in_sizes[7];
  float* out = (float*)d_out;

  // workspace layout
  float* B            = (float*)d_ws;                     // agg1, N*64 fp32
  unsigned char* zb   = (unsigned char*)(B + (size_t)N * 64);   // z1/z2' fp8 N*64
  unsigned char* z3b  = zb + (size_t)N * 64;              // z3, N*16 fp8
  int* cntA  = (int*)(z3b + (size_t)N * 16);              // NHB  } one memset
  float* cs1 = (float*)(cntA + NHB);                      // 64   } covers
  float* cs2 = cs1 + 64;                                  // 64   } these 3
  float* cm2w = cs2 + 64;                                 // 64 (no memset needed)
  int* baseA    = (int*)(cm2w + 64);                      // NHB+1
  int* curA     = baseA + NHB + 1;                        // NHB
  int* rowstart = curA + NHB;                             // N+1
  int* csr      = rowstart + N + 1;                       // E
  // ppack aliases zb+z3b (dead until matnorm1 writes zb, after fillsort)
  unsigned* ppack = (unsigned*)zb;
  // o (bf16 N*64 = N*32 uints) aliases B (dead after matnorm2 reads it)
  unsigned* ob = (unsigned*)B;

  const int NHI = (N + 1023) >> 10;     // 98
  const int node_blocks = (N + 3) / 4;  // 4 waves of 64 per block
  const int npairs = (N + 1) / 2;
  const int pair_blocks = (npairs + 3) / 4;  // 4 pair-waves per block
  const float invN = 1.0f / (float)N;

  // ---- CSR build + layer-1 colsum ----
  hipMemsetAsync(cntA, 0, (NHB + 128) * sizeof(int), stream);  // cntA+cs1+cs2
  prelude_kernel<<<512, 256, 0, stream>>>(dst, cntA, E, feat, cs1, N * 16);
  scanA_kernel<<<1, NHB, 0, stream>>>(cntA, baseA, curA, NHI);
  scatterA_kernel<<<512, 256, 0, stream>>>(src, dst, curA, ppack, E);
  fillsort_kernel<<<2 * NHI, 512, 0, stream>>>(ppack, baseA, rowstart, csr, N, E);

  // ---- layer 1 (split-lane pair gather) ----
  matnorm_kernel<<<1024, 256, 0, stream>>>(feat, W1, cs1, zb, N, invN);
  gather64_kernel<<<pair_blocks, 256, 0, stream>>>(zb, b1, rowstart, csr, B, N);

  // ---- layer 2: matnorm2 emits UNcentered z2' and accumulates cs2 itself ----
  matnorm2_kernel<<<1024, 256, 0, stream>>>(B, W2, cs2, zb, N);
  cm2_kernel<<<1, 64, 0, stream>>>(cs2, W2, cm2w, invN);
  gather_l2_kernel<<<pair_blocks, 256, 0, stream>>>(zb, b2, cm2w, rowstart, csr,
                                                    ob, N);
  w3mat_kernel<<<node_blocks, 256, 0, stream>>>((const unsigned short*)ob, W3,
                                                z3b, N);

  // ---- layer 3 final aggregation ----
  gather16_kernel<<<node_blocks, 256, 0, stream>>>(z3b, b3, rowstart, csr, out, N);
}

// Round 20
// 355.071 us; speedup vs baseline: 1.0625x; 1.0192x over previous
//
#include <hip/hip_runtime.h>
#include <hip/hip_fp8.h>

// GCN: N=100000 nodes, E=1600000 edges, F_IN=F_HID=64, F_OUT=16, fp32.
//
// R32 -> R33: matnorm2 sits at 44% VALU / 5% HBM -- neither pipe bound.
// VALU floor model: 100k rows x ~140 ops x 2cy / 1024 SIMDs ~= 11us vs 47
// measured => per-row DEPENDENCY CHAIN limited (load -> shfl reduce ->
// rsqrt -> 4 FMA chains), and 2 waves/SIMD can't fill the pipe. R31 proved
// more WAVES regress (preamble-dominated); untested axis = more ILP/wave.
// R33: ROW-PAIR ILP -- each wave iteration processes rows (2i, 2i+1):
// 2 independent loads, interleaved reductions, 8 concurrent FMA chains
// sharing w[k]. Wave count/grid/preamble/total rows unchanged; +~10 VGPR
// (no occupancy step at 2 waves/SIMD). Both matnorms; all else R32 exact.

#define NHB 128     // max hi-buckets of 1024 nodes (N <= 131072); hi = dst >> 10

typedef float floatx2 __attribute__((ext_vector_type(2)));

__device__ __forceinline__ unsigned short f2bf(float f) {
  unsigned u = __builtin_bit_cast(unsigned, f);
  u += 0x7FFFu + ((u >> 16) & 1u);    // round-to-nearest-even
  return (unsigned short)(u >> 16);
}
__device__ __forceinline__ float bf2f(unsigned short h) {
  return __builtin_bit_cast(float, ((unsigned)h) << 16);
}
__device__ __forceinline__ float rlane(float v, int k) {
  return __builtin_bit_cast(
      float, __builtin_amdgcn_readlane(__builtin_bit_cast(int, v), k));
}
__device__ __forceinline__ unsigned char f2fp8(float f) {
  __hip_fp8_e4m3 t(f);                // RNE, saturate-to-finite (OCP)
  return (unsigned char)t.__x;
}
// hardware OCP e4m3 -> f32 (gfx950); exact fallback via f16-embedding.
__device__ __forceinline__ float fp8tof(unsigned v) {
#if __has_builtin(__builtin_amdgcn_cvt_f32_fp8)
  return __builtin_amdgcn_cvt_f32_fp8((int)v, 0);
#else
  const unsigned h = ((v << 8) & 0x8000u) | ((v << 7) & 0x3f80u);
  __half_raw hr; hr.x = (unsigned short)h;
  return (float)__half(hr) * 256.0f;
#endif
}
// packed pair decode: 2 fp8 bytes -> 2 floats in one instruction
__device__ __forceinline__ floatx2 fp8x2tof(unsigned short p) {
#if __has_builtin(__builtin_amdgcn_cvt_pk_f32_fp8)
  return __builtin_amdgcn_cvt_pk_f32_fp8((int)(unsigned)p, false);
#else
  floatx2 r; r.x = fp8tof(p & 0xffu); r.y = fp8tof(p >> 8); return r;
#endif
}

// ------- prelude: cntA histogram of dst (hi-buckets) + column sums of feat -------
__global__ __launch_bounds__(256) void prelude_kernel(
    const int* __restrict__ dst, int* __restrict__ cntA, int E,
    const float* __restrict__ x, float* __restrict__ cs, int n4) {
  __shared__ int lc[NHB];
  __shared__ float lds[16][64];
  const int t = threadIdx.x;
  if (t < NHB) lc[t] = 0;
  __syncthreads();
  const int stride = gridDim.x * blockDim.x;
  for (int e = blockIdx.x * blockDim.x + t; e < E; e += stride)
    atomicAdd(&lc[__builtin_nontemporal_load(&dst[e]) >> 10], 1);

  float s0 = 0.f, s1 = 0.f, s2 = 0.f, s3 = 0.f;
  for (int i = blockIdx.x * blockDim.x + t; i < n4; i += stride) {
    float4 v = ((const float4*)x)[i];
    s0 += v.x; s1 += v.y; s2 += v.z; s3 += v.w;
  }
  const int r = t >> 4;
  const int cq = (t & 15) * 4;
  lds[r][cq + 0] = s0; lds[r][cq + 1] = s1; lds[r][cq + 2] = s2; lds[r][cq + 3] = s3;
  __syncthreads();
  if (t < NHB && lc[t]) atomicAdd(&cntA[t], lc[t]);
  if (t < 64) {
    float tot = 0.f;
    #pragma unroll
    for (int rr = 0; rr < 16; ++rr) tot += lds[rr][t];
    unsafeAtomicAdd(&cs[t], tot);
  }
}

// ------- layer1: z = (x @ W) * rinv - cm, fp8 out; ROW-PAIR ILP -------
__global__ __launch_bounds__(256) void matnorm_kernel(
    const float* x, const float* __restrict__ W,
    const float* __restrict__ cs, unsigned char* __restrict__ z,
    int N, float invN) {
  const int lane = threadIdx.x & 63;
  const int wid  = blockIdx.x * (blockDim.x >> 6) + (threadIdx.x >> 6);
  const int nw   = gridDim.x * (blockDim.x >> 6);

  float w[64];
  float cm0 = 0.f, cm1 = 0.f, cm2 = 0.f, cm3 = 0.f;
  #pragma unroll
  for (int k = 0; k < 64; k += 4) {
    w[k + 0] = W[(k + 0) * 64 + lane];
    w[k + 1] = W[(k + 1) * 64 + lane];
    w[k + 2] = W[(k + 2) * 64 + lane];
    w[k + 3] = W[(k + 3) * 64 + lane];
    cm0 = fmaf(cs[k + 0], w[k + 0], cm0);
    cm1 = fmaf(cs[k + 1], w[k + 1], cm1);
    cm2 = fmaf(cs[k + 2], w[k + 2], cm2);
    cm3 = fmaf(cs[k + 3], w[k + 3], cm3);
  }
  const float cm = ((cm0 + cm1) + (cm2 + cm3)) * invN;

  const int npair = (N + 1) >> 1;
  for (int rp = wid; rp < npair; rp += nw) {
    const int r0 = rp << 1;
    const int r1 = r0 + 1;
    const bool h1 = (r1 < N);
    const float xv0 = x[(size_t)r0 * 64 + lane];
    const float xv1 = h1 ? x[(size_t)r1 * 64 + lane] : 0.f;
    float ss0 = xv0 * xv0, ss1 = xv1 * xv1;
    #pragma unroll
    for (int m = 1; m < 64; m <<= 1) {
      ss0 += __shfl_xor(ss0, m, 64);
      ss1 += __shfl_xor(ss1, m, 64);
    }
    const float rinv0 = 1.0f / sqrtf(1e-6f + ss0);
    const float rinv1 = 1.0f / sqrtf(1e-6f + ss1);
    float a0 = 0.f, a1 = 0.f, a2 = 0.f, a3 = 0.f;
    float c0 = 0.f, c1 = 0.f, c2 = 0.f, c3 = 0.f;
    #pragma unroll
    for (int k = 0; k < 64; k += 4) {
      a0 = fmaf(rlane(xv0, k + 0), w[k + 0], a0);
      c0 = fmaf(rlane(xv1, k + 0), w[k + 0], c0);
      a1 = fmaf(rlane(xv0, k + 1), w[k + 1], a1);
      c1 = fmaf(rlane(xv1, k + 1), w[k + 1], c1);
      a2 = fmaf(rlane(xv0, k + 2), w[k + 2], a2);
      c2 = fmaf(rlane(xv1, k + 2), w[k + 2], c2);
      a3 = fmaf(rlane(xv0, k + 3), w[k + 3], a3);
      c3 = fmaf(rlane(xv1, k + 3), w[k + 3], c3);
    }
    const float acc0 = (a0 + a1) + (a2 + a3);
    const float acc1 = (c0 + c1) + (c2 + c3);
    z[(size_t)r0 * 64 + lane] = f2fp8(acc0 * rinv0 - cm);
    if (h1) z[(size_t)r1 * 64 + lane] = f2fp8(acc1 * rinv1 - cm);
  }
}

// ------- layer2: z2' = (x @ W) * rinv (UNcentered), fp8 out; cs += colsum(x);
//         ROW-PAIR ILP -------
__global__ __launch_bounds__(256) void matnorm2_kernel(
    const float* x, const float* __restrict__ W,
    float* __restrict__ cs, unsigned char* __restrict__ z, int N) {
  __shared__ float lred[4][64];
  const int lane = threadIdx.x & 63;
  const int wv   = threadIdx.x >> 6;
  const int wid  = blockIdx.x * (blockDim.x >> 6) + wv;
  const int nw   = gridDim.x * (blockDim.x >> 6);

  float w[64];
  #pragma unroll
  for (int k = 0; k < 64; k += 4) {
    w[k + 0] = W[(k + 0) * 64 + lane];
    w[k + 1] = W[(k + 1) * 64 + lane];
    w[k + 2] = W[(k + 2) * 64 + lane];
    w[k + 3] = W[(k + 3) * 64 + lane];
  }

  float csum = 0.f;
  const int npair = (N + 1) >> 1;
  for (int rp = wid; rp < npair; rp += nw) {
    const int r0 = rp << 1;
    const int r1 = r0 + 1;
    const bool h1 = (r1 < N);
    const float xv0 = x[(size_t)r0 * 64 + lane];
    const float xv1 = h1 ? x[(size_t)r1 * 64 + lane] : 0.f;
    csum += xv0 + xv1;
    float ss0 = xv0 * xv0, ss1 = xv1 * xv1;
    #pragma unroll
    for (int m = 1; m < 64; m <<= 1) {
      ss0 += __shfl_xor(ss0, m, 64);
      ss1 += __shfl_xor(ss1, m, 64);
    }
    const float rinv0 = 1.0f / sqrtf(1e-6f + ss0);
    const float rinv1 = 1.0f / sqrtf(1e-6f + ss1);
    float a0 = 0.f, a1 = 0.f, a2 = 0.f, a3 = 0.f;
    float c0 = 0.f, c1 = 0.f, c2 = 0.f, c3 = 0.f;
    #pragma unroll
    for (int k = 0; k < 64; k += 4) {
      a0 = fmaf(rlane(xv0, k + 0), w[k + 0], a0);
      c0 = fmaf(rlane(xv1, k + 0), w[k + 0], c0);
      a1 = fmaf(rlane(xv0, k + 1), w[k + 1], a1);
      c1 = fmaf(rlane(xv1, k + 1), w[k + 1], c1);
      a2 = fmaf(rlane(xv0, k + 2), w[k + 2], a2);
      c2 = fmaf(rlane(xv1, k + 2), w[k + 2], c2);
      a3 = fmaf(rlane(xv0, k + 3), w[k + 3], a3);
      c3 = fmaf(rlane(xv1, k + 3), w[k + 3], c3);
    }
    const float acc0 = (a0 + a1) + (a2 + a3);
    const float acc1 = (c0 + c1) + (c2 + c3);
    z[(size_t)r0 * 64 + lane] = f2fp8(acc0 * rinv0);
    if (h1) z[(size_t)r1 * 64 + lane] = f2fp8(acc1 * rinv1);
  }
  lred[wv][lane] = csum;
  __syncthreads();
  if (threadIdx.x < 64) {
    const float tot = lred[0][lane] + lred[1][lane] + lred[2][lane] + lred[3][lane];
    unsafeAtomicAdd(&cs[lane], tot);
  }
}

// ------- cm2[m] = invN * sum_k cs2[k] * W2[k][m]  (1 wave) -------
__global__ void cm2_kernel(const float* __restrict__ cs,
                           const float* __restrict__ W,
                           float* __restrict__ cm2, float invN) {
  const int m = threadIdx.x;   // 64
  float a0 = 0.f, a1 = 0.f, a2 = 0.f, a3 = 0.f;
  #pragma unroll
  for (int k = 0; k < 64; k += 4) {
    a0 = fmaf(cs[k + 0], W[(k + 0) * 64 + m], a0);
    a1 = fmaf(cs[k + 1], W[(k + 1) * 64 + m], a1);
    a2 = fmaf(cs[k + 2], W[(k + 2) * 64 + m], a2);
    a3 = fmaf(cs[k + 3], W[(k + 3) * 64 + m], a3);
  }
  cm2[m] = ((a0 + a1) + (a2 + a3)) * invN;
}

// ================= CSR build: hi-bucket radix + LDS counting sort =================
// Edge packed as (src << 10) | (dst & 1023): src < 2^17 -> 27 bits used.

// 128-thread LDS Hillis-Steele exclusive scan over the hi-bucket counts.
__global__ void scanA_kernel(const int* __restrict__ cntA,
                             int* __restrict__ baseA, int* __restrict__ curA,
                             int NHI) {
  __shared__ int s[NHB];
  const int t = threadIdx.x;   // 128
  const int v = (t < NHI) ? cntA[t] : 0;
  s[t] = v;
  __syncthreads();
  int acc = v;
  for (int off = 1; off < NHB; off <<= 1) {
    const int add = (t >= off) ? s[t - off] : 0;
    __syncthreads();
    acc += add;
    s[t] = acc;
    __syncthreads();
  }
  const int excl = acc - v;
  if (t < NHI) { baseA[t] = excl; curA[t] = excl; }
  if (t == NHI - 1) baseA[NHI] = acc;
}

#define TILE 2048
#define CAPA 48   // per-tile per-bucket mean 21, sigma 4.6 -> ~6 sigma + spill
__global__ __launch_bounds__(256) void scatterA_kernel(
    const int* __restrict__ src, const int* __restrict__ dst,
    int* __restrict__ curA, unsigned* __restrict__ ppack, int E) {
  __shared__ unsigned lpk[NHB][CAPA];
  __shared__ int lcnt[NHB], lbase[NHB];
  const int t = threadIdx.x;
  if (t < NHB) lcnt[t] = 0;
  __syncthreads();
  const int ntiles = (E + TILE - 1) / TILE;
  for (int tile = blockIdx.x; tile < ntiles; tile += gridDim.x) {
    const int base = tile * TILE;
    #pragma unroll
    for (int j = 0; j < TILE / 256; ++j) {
      const int e = base + j * 256 + t;   // coalesced
      if (e < E) {
        const int d = __builtin_nontemporal_load(&dst[e]);
        const int s = __builtin_nontemporal_load(&src[e]);
        const unsigned pw = ((unsigned)s << 10) | ((unsigned)d & 1023u);
        const int p = d >> 10;
        const int slot = atomicAdd(&lcnt[p], 1);
        if (slot < CAPA) lpk[p][slot] = pw;
        else ppack[atomicAdd(&curA[p], 1)] = pw;  // rare spill
      }
    }
    __syncthreads();
    if (t < NHB) {
      int c = lcnt[t]; if (c > CAPA) c = CAPA;
      lbase[t] = c ? atomicAdd(&curA[t], c) : 0;
      lcnt[t] = c;
    }
    __syncthreads();
    for (int p = 0; p < NHB; ++p) {
      const int c = lcnt[p];
      if (t < c) ppack[lbase[p] + t] = lpk[p][t];  // contiguous chunk
    }
    __syncthreads();
    if (t < NHB) lcnt[t] = 0;
    __syncthreads();
  }
}

// One workgroup (512 thr) per 512-node HALF-bucket. ALL threads participate
// in every phase (no predicated barriers). Filter parent ppack range by bit9
// of the low-10 dst bits; 512-bin LDS counting sort; 4-deep ILP.
// half-1 base = ehi - own_total (half-0 rows precede half-1 in dst order).
__global__ __launch_bounds__(512) void fillsort_kernel(
    const unsigned* __restrict__ ppack, const int* __restrict__ baseA,
    int* __restrict__ rowstart, int* __restrict__ csr, int N, int E) {
  __shared__ int hist[512];
  __shared__ int bs[512];
  const int t = threadIdx.x;          // 512
  const int hb = blockIdx.x;          // half-bucket id
  const int parent = hb >> 1;
  const unsigned half = (unsigned)(hb & 1);
  const int nlo = hb << 9;            // first node of this half
  const int elo = baseA[parent], ehi = baseA[parent + 1];

  hist[t] = 0;
  __syncthreads();

  // phase 1: histogram own half (4 independent loads in flight)
  int e = elo + t;
  for (; e + 3 * 512 < ehi; e += 4 * 512) {
    const unsigned p0 = ppack[e],           p1 = ppack[e + 512];
    const unsigned p2 = ppack[e + 2 * 512], p3 = ppack[e + 3 * 512];
    if (((p0 >> 9) & 1u) == half) atomicAdd(&hist[p0 & 511u], 1);
    if (((p1 >> 9) & 1u) == half) atomicAdd(&hist[p1 & 511u], 1);
    if (((p2 >> 9) & 1u) == half) atomicAdd(&hist[p2 & 511u], 1);
    if (((p3 >> 9) & 1u) == half) atomicAdd(&hist[p3 & 511u], 1);
  }
  for (; e < ehi; e += 512) {
    const unsigned p = ppack[e];
    if (((p >> 9) & 1u) == half) atomicAdd(&hist[p & 511u], 1);
  }
  __syncthreads();

  // exclusive scan over 512 bins (all 512 threads; 9 rounds)
  const int c = hist[t];
  bs[t] = c;
  __syncthreads();
  for (int off = 1; off < 512; off <<= 1) {
    const int v = (t >= off) ? bs[t - off] : 0;
    __syncthreads();
    bs[t] += v;
    __syncthreads();
  }
  const int excl = bs[t] - c;
  const int total = bs[511];
  const int halfbase = half ? (ehi - total) : elo;

  hist[t] = excl;                     // LDS cursor
  const int n0 = nlo + t;
  if (n0 < N) rowstart[n0] = halfbase + excl;
  if (hb == 0 && t == 0) rowstart[N] = E;
  __syncthreads();

  // phase 2: place own half (csr window ~32KB, single CU owner)
  e = elo + t;
  for (; e + 3 * 512 < ehi; e += 4 * 512) {
    const unsigned p0 = ppack[e],           p1 = ppack[e + 512];
    const unsigned p2 = ppack[e + 2 * 512], p3 = ppack[e + 3 * 512];
    if (((p0 >> 9) & 1u) == half)
      csr[halfbase + atomicAdd(&hist[p0 & 511u], 1)] = (int)(p0 >> 10);
    if (((p1 >> 9) & 1u) == half)
      csr[halfbase + atomicAdd(&hist[p1 & 511u], 1)] = (int)(p1 >> 10);
    if (((p2 >> 9) & 1u) == half)
      csr[halfbase + atomicAdd(&hist[p2 & 511u], 1)] = (int)(p2 >> 10);
    if (((p3 >> 9) & 1u) == half)
      csr[halfbase + atomicAdd(&hist[p3 & 511u], 1)] = (int)(p3 >> 10);
  }
  for (; e < ehi; e += 512) {
    const unsigned p = ppack[e];
    if (((p >> 9) & 1u) == half)
      csr[halfbase + atomicAdd(&hist[p & 511u], 1)] = (int)(p >> 10);
  }
}

// ------- gather64 (split-lane pair): agg[d] = relu(z[d] + b + sum z[src]) -------
// Wave = 2 nodes; half h serves node n0+h, lane owns features (2*il, 2*il+1).
// One ushort VMEM per j serves one edge of EACH half (0.5 instr/edge).
// Proven form (R22/R23) -- do not restructure.
__global__ __launch_bounds__(256) void gather64_kernel(
    const unsigned char* __restrict__ z, const float* __restrict__ b,
    const int* __restrict__ rowstart, const int* __restrict__ csr,
    float* __restrict__ agg, int N) {
  const int lane = threadIdx.x & 63;
  const int h    = lane >> 5;
  const int il   = lane & 31;
  const int f0   = il << 1;
  const int pair = blockIdx.x * (blockDim.x >> 6) + (threadIdx.x >> 6);
  const int n0 = pair << 1;
  if (n0 >= N) return;
  const int node = n0 + h;
  const bool hv = (node < N);
  const int start = hv ? rowstart[node] : 0;
  const int end   = hv ? rowstart[node + 1] : 0;
  const int deg   = end - start;
  const int degA = __builtin_amdgcn_readfirstlane(deg);
  const int degB = __builtin_amdgcn_readlane(deg, 32);
  const int maxdeg = degA > degB ? degA : degB;

  const unsigned char* zp = z + f0;
  const unsigned short sv =
      hv ? *(const unsigned short*)(zp + (size_t)node * 64) : (unsigned short)0;

  float a00 = 0.f, a01 = 0.f, a10 = 0.f, a11 = 0.f;
  for (int w0 = 0; w0 < maxdeg; w0 += 32) {
    const int ei = start + w0 + il;
    const int safe = (ei < end) ? ei : (end > start ? end - 1 : 0);
    const int cidx = csr[safe];
    const int rem = maxdeg - w0;
    const int nloc = rem < 32 ? rem : 32;
    int j0 = 0;
    for (; j0 + 16 <= nloc; j0 += 16) {
      int idx[16];
      #pragma unroll
      for (int j = 0; j < 16; ++j)
        idx[j] = __shfl(cidx, (h << 5) + j0 + j, 64);
      unsigned short hh[16];
      #pragma unroll
      for (int j = 0; j < 16; ++j)
        hh[j] = *(const unsigned short*)(zp + (size_t)(unsigned)idx[j] * 64u);
      #pragma unroll
      for (int j = 0; j < 16; ++j) {
        const unsigned short m = (w0 + j0 + j < deg) ? hh[j] : (unsigned short)0;
        const floatx2 v = fp8x2tof(m);
        if (j & 1) { a10 += v.x; a11 += v.y; }
        else       { a00 += v.x; a01 += v.y; }
      }
    }
    for (; j0 + 4 <= nloc; j0 += 4) {
      int idx[4];
      #pragma unroll
      for (int j = 0; j < 4; ++j)
        idx[j] = __shfl(cidx, (h << 5) + j0 + j, 64);
      unsigned short hh[4];
      #pragma unroll
      for (int j = 0; j < 4; ++j)
        hh[j] = *(const unsigned short*)(zp + (size_t)(unsigned)idx[j] * 64u);
      #pragma unroll
      for (int j = 0; j < 4; ++j) {
        const unsigned short m = (w0 + j0 + j < deg) ? hh[j] : (unsigned short)0;
        const floatx2 v = fp8x2tof(m);
        if (j & 1) { a10 += v.x; a11 += v.y; }
        else       { a00 += v.x; a01 += v.y; }
      }
    }
    for (; j0 < nloc; ++j0) {
      const int idx = __shfl(cidx, (h << 5) + j0, 64);
      const unsigned short hh =
          *(const unsigned short*)(zp + (size_t)(unsigned)idx * 64u);
      const unsigned short m = (w0 + j0 < deg) ? hh : (unsigned short)0;
      const floatx2 v = fp8x2tof(m);
      a00 += v.x; a01 += v.y;
    }
  }
  if (hv) {
    const floatx2 sf = fp8x2tof(sv);
    const float2 bb = *(const float2*)(b + f0);
    float2 st;
    st.x = fmaxf(sf.x + bb.x + a00 + a10, 0.f);
    st.y = fmaxf(sf.y + bb.y + a01 + a11, 0.f);
    *(float2*)(agg + (size_t)node * 64 + f0) = st;
  }
}

// ------- gather_l2 (split-lane pair): o = relu(sum z2' - (deg+1)*cm2 + b2) ------
// Structure IDENTICAL to gather64 (VGPR ~36, 0.5 instr/edge); o stored as
// bf16 pairs (packed uint per lane). W3 matvec moved to w3mat_kernel.
__global__ __launch_bounds__(256) void gather_l2_kernel(
    const unsigned char* __restrict__ z2, const float* __restrict__ b2,
    const float* __restrict__ cm2, const int* __restrict__ rowstart,
    const int* __restrict__ csr, unsigned* __restrict__ o, int N) {
  const int lane = threadIdx.x & 63;
  const int h    = lane >> 5;
  const int il   = lane & 31;
  const int f0   = il << 1;
  const int pair = blockIdx.x * (blockDim.x >> 6) + (threadIdx.x >> 6);
  const int n0 = pair << 1;
  if (n0 >= N) return;
  const int node = n0 + h;
  const bool hv = (node < N);
  const int start = hv ? rowstart[node] : 0;
  const int end   = hv ? rowstart[node + 1] : 0;
  const int deg   = end - start;
  const int degA = __builtin_amdgcn_readfirstlane(deg);
  const int degB = __builtin_amdgcn_readlane(deg, 32);
  const int maxdeg = degA > degB ? degA : degB;

  const unsigned char* zp = z2 + f0;
  const unsigned short sv =
      hv ? *(const unsigned short*)(zp + (size_t)node * 64) : (unsigned short)0;

  float a00 = 0.f, a01 = 0.f, a10 = 0.f, a11 = 0.f;
  for (int w0 = 0; w0 < maxdeg; w0 += 32) {
    const int ei = start + w0 + il;
    const int safe = (ei < end) ? ei : (end > start ? end - 1 : 0);
    const int cidx = csr[safe];
    const int rem = maxdeg - w0;
    const int nloc = rem < 32 ? rem : 32;
    int j0 = 0;
    for (; j0 + 16 <= nloc; j0 += 16) {
      int idx[16];
      #pragma unroll
      for (int j = 0; j < 16; ++j)
        idx[j] = __shfl(cidx, (h << 5) + j0 + j, 64);
      unsigned short hh[16];
      #pragma unroll
      for (int j = 0; j < 16; ++j)
        hh[j] = *(const unsigned short*)(zp + (size_t)(unsigned)idx[j] * 64u);
      #pragma unroll
      for (int j = 0; j < 16; ++j) {
        const unsigned short m = (w0 + j0 + j < deg) ? hh[j] : (unsigned short)0;
        const floatx2 v = fp8x2tof(m);
        if (j & 1) { a10 += v.x; a11 += v.y; }
        else       { a00 += v.x; a01 += v.y; }
      }
    }
    for (; j0 + 4 <= nloc; j0 += 4) {
      int idx[4];
      #pragma unroll
      for (int j = 0; j < 4; ++j)
        idx[j] = __shfl(cidx, (h << 5) + j0 + j, 64);
      unsigned short hh[4];
      #pragma unroll
      for (int j = 0; j < 4; ++j)
        hh[j] = *(const unsigned short*)(zp + (size_t)(unsigned)idx[j] * 64u);
      #pragma unroll
      for (int j = 0; j < 4; ++j) {
        const unsigned short m = (w0 + j0 + j < deg) ? hh[j] : (unsigned short)0;
        const floatx2 v = fp8x2tof(m);
        if (j & 1) { a10 += v.x; a11 += v.y; }
        else       { a00 += v.x; a01 += v.y; }
      }
    }
    for (; j0 < nloc; ++j0) {
      const int idx = __shfl(cidx, (h << 5) + j0, 64);
      const unsigned short hh =
          *(const unsigned short*)(zp + (size_t)(unsigned)idx * 64u);
      const unsigned short m = (w0 + j0 < deg) ? hh : (unsigned short)0;
      const floatx2 v = fp8x2tof(m);
      a00 += v.x; a01 += v.y;
    }
  }
  if (hv) {
    const floatx2 sf = fp8x2tof(sv);
    const float2 bb = *(const float2*)(b2 + f0);
    const float2 cc = *(const float2*)(cm2 + f0);
    const float dp1 = (float)(deg + 1);
    const float o0 = fmaxf(sf.x + bb.x + (a00 + a10) - dp1 * cc.x, 0.f);
    const float o1 = fmaxf(sf.y + bb.y + (a01 + a11) - dp1 * cc.y, 0.f);
    o[(size_t)node * 32 + il] =
        (unsigned)f2bf(o0) | ((unsigned)f2bf(o1) << 16);
  }
}

// ------- w3mat: z3 = o @ W3 (streaming; one wave per node) -------
// Lane owns W3 row `lane`; 16 partials o[lane]*W3[lane][m]; split-butterfly
// reduction; lane l<16 stores output column bitrev4(l) as fp8.
__global__ __launch_bounds__(256) void w3mat_kernel(
    const unsigned short* __restrict__ o16, const float* __restrict__ W3,
    unsigned char* __restrict__ z3, int N) {
  const int lane = threadIdx.x & 63;
  int node = blockIdx.x * (blockDim.x >> 6) + (threadIdx.x >> 6);
  if (node >= N) return;
  node = __builtin_amdgcn_readfirstlane(node);
  float4 w4[4];
  #pragma unroll
  for (int q = 0; q < 4; ++q)
    w4[q] = ((const float4*)(W3 + lane * 16))[q];
  const float o = bf2f(o16[(size_t)node * 64 + lane]);

  float p[16];
  #pragma unroll
  for (int q = 0; q < 4; ++q) {
    p[4 * q + 0] = o * w4[q].x;
    p[4 * q + 1] = o * w4[q].y;
    p[4 * q + 2] = o * w4[q].z;
    p[4 * q + 3] = o * w4[q].w;
  }
  {
    const bool up = (lane & 1);
    #pragma unroll
    for (int m = 0; m < 8; ++m) {
      const float mine = up ? p[m + 8] : p[m];
      const float give = up ? p[m] : p[m + 8];
      p[m] = mine + __shfl_xor(give, 1, 64);
    }
  }
  {
    const bool up = (lane & 2);
    #pragma unroll
    for (int m = 0; m < 4; ++m) {
      const float mine = up ? p[m + 4] : p[m];
      const float give = up ? p[m] : p[m + 4];
      p[m] = mine + __shfl_xor(give, 2, 64);
    }
  }
  {
    const bool up = (lane & 4);
    #pragma unroll
    for (int m = 0; m < 2; ++m) {
      const float mine = up ? p[m + 2] : p[m];
      const float give = up ? p[m] : p[m + 2];
      p[m] = mine + __shfl_xor(give, 4, 64);
    }
  }
  {
    const bool up = (lane & 8);
    const float mine = up ? p[1] : p[0];
    const float give = up ? p[0] : p[1];
    p[0] = mine + __shfl_xor(give, 8, 64);
  }
  p[0] += __shfl_xor(p[0], 16, 64);
  p[0] += __shfl_xor(p[0], 32, 64);

  if (lane < 16) {
    const int j = ((lane & 1) << 3) | ((lane & 2) << 1) |
                  ((lane & 4) >> 1) | ((lane & 8) >> 3);
    z3[(size_t)node * 16 + j] = f2fp8(p[0]);
  }
}

// ------- gather16: out[d] = z3[d] + b3 + sum z3[src]; 16 feat x 4 edge-groups -------
__global__ __launch_bounds__(256) void gather16_kernel(
    const unsigned char* __restrict__ z3, const float* __restrict__ b3,
    const int* __restrict__ rowstart, const int* __restrict__ csr,
    float* __restrict__ out, int N) {
  const int lane = threadIdx.x & 63;
  const int f = lane & 15;
  const int g = lane >> 4;
  int node = blockIdx.x * (blockDim.x >> 6) + (threadIdx.x >> 6);
  if (node >= N) return;
  node = __builtin_amdgcn_readfirstlane(node);
  const int start = rowstart[node];
  const int end   = rowstart[node + 1];
  float acc0 = 0.f, acc1 = 0.f;
  int e = start + g;
  for (; e + 4 < end; e += 8) {
    acc0 += fp8tof(z3[(size_t)csr[e] * 16 + f]);
    acc1 += fp8tof(z3[(size_t)csr[e + 4] * 16 + f]);
  }
  if (e < end) acc0 += fp8tof(z3[(size_t)csr[e] * 16 + f]);
  float acc = acc0 + acc1;
  acc += __shfl_xor(acc, 16, 64);
  acc += __shfl_xor(acc, 32, 64);
  if (lane < 16)
    out[(size_t)node * 16 + f] = fp8tof(z3[(size_t)node * 16 + f]) + b3[f] + acc;
}

extern "C" void kernel_launch(void* const* d_in, const int* in_sizes, int n_in,
                              void* d_out, int out_size, void* d_ws, size_t ws_size,
                              hipStream_t stream) {
  const float* feat = (const float*)d_in[0];
  const float* W1 = (const float*)d_in[1];
  const float* b1 = (const float*)d_in[2];
  const float* W2 = (const float*)d_in[3];
  const float* b2 = (const float*)d_in[4];
  const float* W3 = (const float*)d_in[5];
  const float* b3 = (const float*)d_in[6];
  const int* src = (const int*)d_in[7];
  const int* dst = (const int*)d_in[8];
  const int N = in_sizes[0] / 64;
  const int E = in_sizes[7];
  float* out = (float*)d_out;

  // workspace layout
  float* B            = (float*)d_ws;                     // agg1, N*64 fp32
  unsigned char* zb   = (unsigned char*)(B + (size_t)N * 64);   // z1/z2' fp8 N*64
  unsigned char* z3b  = zb + (size_t)N * 64;              // z3, N*16 fp8
  int* cntA  = (int*)(z3b + (size_t)N * 16);              // NHB  } one memset
  float* cs1 = (float*)(cntA + NHB);                      // 64   } covers
  float* cs2 = cs1 + 64;                                  // 64   } these 3
  float* cm2w = cs2 + 64;                                 // 64 (no memset needed)
  int* baseA    = (int*)(cm2w + 64);                      // NHB+1
  int* curA     = baseA + NHB + 1;                        // NHB
  int* rowstart = curA + NHB;                             // N+1
  int* csr      = rowstart + N + 1;                       // E
  // ppack aliases zb+z3b (dead until matnorm1 writes zb, after fillsort)
  unsigned* ppack = (unsigned*)zb;
  // o (bf16 N*64 = N*32 uints) aliases B (dead after matnorm2 reads it)
  unsigned* ob = (unsigned*)B;

  const int NHI = (N + 1023) >> 10;     // 98
  const int node_blocks = (N + 3) / 4;  // 4 waves of 64 per block
  const int npairs = (N + 1) / 2;
  const int pair_blocks = (npairs + 3) / 4;  // 4 pair-waves per block
  const float invN = 1.0f / (float)N;

  // ---- CSR build + layer-1 colsum ----
  hipMemsetAsync(cntA, 0, (NHB + 128) * sizeof(int), stream);  // cntA+cs1+cs2
  prelude_kernel<<<512, 256, 0, stream>>>(dst, cntA, E, feat, cs1, N * 16);
  scanA_kernel<<<1, NHB, 0, stream>>>(cntA, baseA, curA, NHI);
  scatterA_kernel<<<512, 256, 0, stream>>>(src, dst, curA, ppack, E);
  fillsort_kernel<<<2 * NHI, 512, 0, stream>>>(ppack, baseA, rowstart, csr, N, E);

  // ---- layer 1 (split-lane pair gather) ----
  matnorm_kernel<<<1024, 256, 0, stream>>>(feat, W1, cs1, zb, N, invN);
  gather64_kernel<<<pair_blocks, 256, 0, stream>>>(zb, b1, rowstart, csr, B, N);

  // ---- layer 2: matnorm2 emits UNcentered z2' and accumulates cs2 itself ----
  matnorm2_kernel<<<1024, 256, 0, stream>>>(B, W2, cs2, zb, N);
  cm2_kernel<<<1, 64, 0, stream>>>(cs2, W2, cm2w, invN);
  gather_l2_kernel<<<pair_blocks, 256, 0, stream>>>(zb, b2, cm2w, rowstart, csr,
                                                    ob, N);
  w3mat_kernel<<<node_blocks, 256, 0, stream>>>((const unsigned short*)ob, W3,
                                                z3b, N);

  // ---- layer 3 final aggregation ----
  gather16_kernel<<<node_blocks, 256, 0, stream>>>(z3b, b3, rowstart, csr, out, N);
}